// Round 12
// baseline (260.857 us; speedup 1.0000x reference)
//
#include <hip/hip_runtime.h>
#include <hip/hip_bf16.h>
#include <stdint.h>

#define B_ 2
#define S_ 2048
#define E_ 1024
#define H_ 16
#define DH_ 64
#define MELEMS (4096 * 1024)   // B*S*E
#define WE (1024 * 1024)

typedef unsigned short u16;
typedef __bf16 bf16x8 __attribute__((ext_vector_type(8)));
typedef u16 u16x8 __attribute__((ext_vector_type(8)));
typedef u16 u16x4 __attribute__((ext_vector_type(4)));
typedef float f32x4 __attribute__((ext_vector_type(4)));
typedef uint32_t u32x4 __attribute__((ext_vector_type(4)));

__device__ __forceinline__ float bf2f(u16 u) {
    union { uint32_t i; float f; } v; v.i = ((uint32_t)u) << 16; return v.f;
}
__device__ __forceinline__ u16 f2bf(float f) {   // RNE fp32->bf16
    union { float f; uint32_t i; } v; v.f = f;
    uint32_t r = (v.i + 0x7FFFu + ((v.i >> 16) & 1u)) >> 16;
    return (u16)r;
}
__device__ __forceinline__ uint32_t pkbf(float a, float b) {  // packed cvt
    __hip_bfloat162 h = __float22bfloat162_rn(make_float2(a, b));
    uint32_t r; __builtin_memcpy(&r, &h, 4);   // bit_cast rejected: not TC
    return r;
}
__device__ __forceinline__ bf16x8 ldfrag(const u16* p) {
    u16x8 t = *(const u16x8*)p;
    return __builtin_bit_cast(bf16x8, t);
}
__device__ __forceinline__ void gld16(const void* g, void* l) {
    __builtin_amdgcn_global_load_lds(
        (const __attribute__((address_space(1))) void*)g,
        (__attribute__((address_space(3))) void*)l, 16, 0, 0);
}

// ---------------------------------------------------------------------------
// Weight transpose only (q/k/v conversion fused into gemm_qkv_f):
// W[K][N] fp32 -> Wt[N][K] bf16, LDS-tiled, 65-stride. Grid 1024. (R7-proven)
// ---------------------------------------------------------------------------
__global__ __launch_bounds__(256)
void cvt_w(const float* __restrict__ W0, const float* __restrict__ W1,
           const float* __restrict__ W2, const float* __restrict__ W3,
           u16* __restrict__ T0, u16* __restrict__ T1,
           u16* __restrict__ T2, u16* __restrict__ T3)
{
    __shared__ float tile[64][65];
    const int rr = blockIdx.x;          // 0..1023
    const int tid = threadIdx.x;
    const int z = rr >> 8;
    const int tt = rr & 255;
    const float* W = (z == 0) ? W0 : (z == 1) ? W1 : (z == 2) ? W2 : W3;
    u16* T = (z == 0) ? T0 : (z == 1) ? T1 : (z == 2) ? T2 : T3;
    const int n0 = (tt & 15) * 64, k0 = (tt >> 4) * 64;
    const int r = tid >> 2, c0 = (tid & 3) * 16;

    #pragma unroll
    for (int i = 0; i < 4; ++i) {
        float4 w = *(const float4*)&W[(size_t)(k0 + r) * 1024 + n0 + c0 + i * 4];
        tile[r][c0 + i * 4 + 0] = w.x; tile[r][c0 + i * 4 + 1] = w.y;
        tile[r][c0 + i * 4 + 2] = w.z; tile[r][c0 + i * 4 + 3] = w.w;
    }
    __syncthreads();
    u16x8 a, b;
    #pragma unroll
    for (int j = 0; j < 8; ++j) a[j] = f2bf(tile[c0 + j][r]);
    #pragma unroll
    for (int j = 0; j < 8; ++j) b[j] = f2bf(tile[c0 + 8 + j][r]);
    *(u16x8*)&T[(size_t)(n0 + r) * 1024 + k0 + c0] = a;
    *(u16x8*)&T[(size_t)(n0 + r) * 1024 + k0 + c0 + 8] = b;
}

// ---------------------------------------------------------------------------
// gemm_qkv_f: R11's gemm_bt64<64> structure (512 thr / 8 waves, BK=64, dbuf
// prefetch, T2 XOR swizzle, T1 XCD-chunk) with A read DIRECTLY as fp32 and
// converted in-register during staging (4x float4 -> 8x pkbf -> 2x
// ds_write_b128 into the IDENTICAL swizzled As layout; readers unchanged).
// R7's fusion died on cross-XCD fp32 A re-fetch (FETCH 200MB); the T1 chunk
// now confines each A panel's 16 n-tile re-reads to ONE XCD's L2.
// Replaces cvt_all's 6144-block q/k/v conversion pass (-144 MB streaming).
// ---------------------------------------------------------------------------
__global__ __launch_bounds__(512, 6)
void gemm_qkv_f(const float* __restrict__ A0, const float* __restrict__ A1,
                const float* __restrict__ A2,
                const u16* __restrict__ Bt0, const u16* __restrict__ Bt1,
                const u16* __restrict__ Bt2,
                const float* __restrict__ b0, const float* __restrict__ b1,
                const float* __restrict__ b2,
                u16* __restrict__ C0, u16* __restrict__ C1, u16* __restrict__ C2,
                int vt_z, float scale0)
{
    const int z = blockIdx.z;
    const float* A  = (z == 0) ? A0 : (z == 1) ? A1 : A2;
    const u16* Bt = (z == 0) ? Bt0 : (z == 1) ? Bt1 : Bt2;
    const float* bias = (z == 0) ? b0 : (z == 1) ? b1 : b2;
    u16* C = (z == 0) ? C0 : (z == 1) ? C1 : C2;
    const float scale = (z == 0) ? scale0 : 1.0f;
    const int K = E_;

    __shared__ alignas(16) u16 As[2][128 * 64];
    __shared__ alignas(16) u16 Bs[2][64 * 64];

    const int tid  = threadIdx.x;
    const int lane = tid & 63;
    const int wv   = tid >> 6;       // 0..7
    const int l15  = lane & 15;
    const int quad = lane >> 4;

    // --- T1 XCD-chunked swizzle (nwg = 16*32 = 512, %8==0) ---
    const int nwg = gridDim.x * gridDim.y;
    const int hw  = blockIdx.x + gridDim.x * blockIdx.y;
    const int cpx = nwg >> 3;
    const int lg  = (hw & 7) * cpx + (hw >> 3);
    const int bx  = lg % gridDim.x;
    const int by  = lg / gridDim.x;

    const int m0 = by * 128;
    const int n0 = bx * 64;
    const int wr = (wv >> 1) * 32;
    const int wc = (wv & 1) * 32;

    const int srow8 = tid >> 3;      // 0..63 (B staging)
    const int sp    = tid & 7;
    const int arow  = tid >> 2;      // 0..127 (A staging: 4 thr/row)
    const int ac0   = (tid & 3) * 16;
    const int ab0   = (tid & 3) * 2; // 8-col block index of ac0

    f32x4 acc[2][2] = {};

    auto stageB = [&](int k0, int buf) {
        const int sg = sp ^ (srow8 & 7);
        gld16(&Bt[(size_t)(n0 + srow8) * K + k0 + sg * 8],
              &Bs[buf][srow8 * 64 + sp * 8]);
    };
    auto stageA = [&](int k0, int buf) {
        const float* ap = &A[(size_t)(m0 + arow) * K + k0 + ac0];
        float4 f0 = *(const float4*)(ap + 0);
        float4 f1 = *(const float4*)(ap + 4);
        float4 f2 = *(const float4*)(ap + 8);
        float4 f3 = *(const float4*)(ap + 12);
        u32x4 w0, w1;
        w0[0] = pkbf(f0.x, f0.y); w0[1] = pkbf(f0.z, f0.w);
        w0[2] = pkbf(f1.x, f1.y); w0[3] = pkbf(f1.z, f1.w);
        w1[0] = pkbf(f2.x, f2.y); w1[1] = pkbf(f2.z, f2.w);
        w1[2] = pkbf(f3.x, f3.y); w1[3] = pkbf(f3.z, f3.w);
        *(u32x4*)&As[buf][arow * 64 + ((ab0 ^ (arow & 7)) * 8)]       = w0;
        *(u32x4*)&As[buf][arow * 64 + (((ab0 + 1) ^ (arow & 7)) * 8)] = w1;
    };

    stageB(0, 0);
    stageA(0, 0);
    int cur = 0;

    for (int k0 = 0; k0 < K; k0 += 64) {
        __syncthreads();                 // drains gld16 + ds_writes -> buf[cur] ready
        if (k0 + 64 < K) { stageB(k0 + 64, cur ^ 1); stageA(k0 + 64, cur ^ 1); }

        #pragma unroll
        for (int kk = 0; kk < 2; ++kk) {
            bf16x8 a[2], b[2];
            #pragma unroll
            for (int i = 0; i < 2; ++i) {
                const int R = wr + i * 16 + l15;
                a[i] = ldfrag(&As[cur][R * 64 + (((kk * 4 + quad) ^ (R & 7)) * 8)]);
            }
            #pragma unroll
            for (int j = 0; j < 2; ++j) {
                const int R = wc + j * 16 + l15;
                b[j] = ldfrag(&Bs[cur][R * 64 + (((kk * 4 + quad) ^ (R & 7)) * 8)]);
            }
            #pragma unroll
            for (int i = 0; i < 2; ++i)
                #pragma unroll
                for (int j = 0; j < 2; ++j)
                    acc[i][j] = __builtin_amdgcn_mfma_f32_16x16x32_bf16(
                        a[i], b[j], acc[i][j], 0, 0, 0);
        }
        cur ^= 1;
    }

    #pragma unroll
    for (int j = 0; j < 2; ++j) {
        const int col = n0 + wc + j * 16 + l15;
        const float bcol = bias[col];
        #pragma unroll
        for (int i = 0; i < 2; ++i) {
            if (z == vt_z) {
                const int row0 = m0 + wr + i * 16 + quad * 4;
                const int bb = row0 >> 11, s0 = row0 & 2047;
                u16x4 t;
                #pragma unroll
                for (int r = 0; r < 4; ++r) t[r] = f2bf((acc[i][j][r] + bcol) * scale);
                *(u16x4*)&C[((size_t)bb * E_ + col) * S_ + s0] = t;
            } else {
                #pragma unroll
                for (int r = 0; r < 4; ++r) {
                    const int row = m0 + wr + i * 16 + quad * 4 + r;
                    C[(size_t)row * 1024 + col] = f2bf((acc[i][j][r] + bcol) * scale);
                }
            }
        }
    }
}

// ---------------------------------------------------------------------------
// gemm_bt64 (R11-proven): 512 thr / 8 waves, BK=64, T2, T1, dbuf prefetch.
// Used for the output projection (bf16 A).
// ---------------------------------------------------------------------------
template<int BN>
__global__ __launch_bounds__(512, 6)
void gemm_bt64(const u16* __restrict__ A0, const u16* __restrict__ A1,
               const u16* __restrict__ A2,
               const u16* __restrict__ Bt0, const u16* __restrict__ Bt1,
               const u16* __restrict__ Bt2,
               const float* __restrict__ b0, const float* __restrict__ b1,
               const float* __restrict__ b2,
               void* __restrict__ C0, void* __restrict__ C1, void* __restrict__ C2,
               int c_f32, int vt_z, float scale0, int K)
{
    const int z = blockIdx.z;
    const u16* A  = (z == 0) ? A0 : (z == 1) ? A1 : A2;
    const u16* Bt = (z == 0) ? Bt0 : (z == 1) ? Bt1 : Bt2;
    const float* bias = (z == 0) ? b0 : (z == 1) ? b1 : b2;
    void* C = (z == 0) ? C0 : (z == 1) ? C1 : C2;
    const float scale = (z == 0) ? scale0 : 1.0f;

    __shared__ alignas(16) u16 As[2][128 * 64];
    __shared__ alignas(16) u16 Bs[2][BN * 64];

    const int tid  = threadIdx.x;
    const int lane = tid & 63;
    const int wv   = tid >> 6;       // 0..7
    const int l15  = lane & 15;
    const int quad = lane >> 4;

    // --- T1 XCD-chunked swizzle (bijective; nwg%8==0 by launch config) ---
    const int nwg = gridDim.x * gridDim.y;
    const int hw  = blockIdx.x + gridDim.x * blockIdx.y;
    const int cpx = nwg >> 3;
    const int lg  = (hw & 7) * cpx + (hw >> 3);
    const int bx  = lg % gridDim.x;
    const int by  = lg / gridDim.x;

    const int m0 = by * 128;
    const int n0 = bx * BN;
    const int wr = (wv >> 1) * 32;          // 4 row-quarters of 32
    const int wc = (wv & 1) * (BN / 2);     // 2 col-halves

    const int srow8 = tid >> 3;      // 0..63
    const int sp    = tid & 7;       // 16B col-block within 64-col row

    constexpr int NJ = BN / 32;
    f32x4 acc[2][NJ] = {};

    auto stage = [&](int k0, int buf) {
        #pragma unroll
        for (int g = 0; g < 2; ++g) {           // A: 128 rows, 64 rows/round
            const int r = g * 64 + srow8;
            const int sg = sp ^ (r & 7);
            gld16(&A[(size_t)(m0 + r) * K + k0 + sg * 8],
                  &As[buf][r * 64 + sp * 8]);
        }
        #pragma unroll
        for (int g = 0; g < BN / 64; ++g) {     // B: BN rows
            const int r = g * 64 + srow8;
            const int sg = sp ^ (r & 7);
            gld16(&Bt[(size_t)(n0 + r) * K + k0 + sg * 8],
                  &Bs[buf][r * 64 + sp * 8]);
        }
    };

    stage(0, 0);
    int cur = 0;

    for (int k0 = 0; k0 < K; k0 += 64) {
        __syncthreads();                         // drains gld16 -> buf[cur] ready
        if (k0 + 64 < K) stage(k0 + 64, cur ^ 1);  // prefetch next K-tile

        #pragma unroll
        for (int kk = 0; kk < 2; ++kk) {
            bf16x8 a[2], b[NJ];
            #pragma unroll
            for (int i = 0; i < 2; ++i) {
                const int R = wr + i * 16 + l15;
                a[i] = ldfrag(&As[cur][R * 64 + (((kk * 4 + quad) ^ (R & 7)) * 8)]);
            }
            #pragma unroll
            for (int j = 0; j < NJ; ++j) {
                const int R = wc + j * 16 + l15;
                b[j] = ldfrag(&Bs[cur][R * 64 + (((kk * 4 + quad) ^ (R & 7)) * 8)]);
            }
            #pragma unroll
            for (int i = 0; i < 2; ++i)
                #pragma unroll
                for (int j = 0; j < NJ; ++j)
                    acc[i][j] = __builtin_amdgcn_mfma_f32_16x16x32_bf16(
                        a[i], b[j], acc[i][j], 0, 0, 0);
        }
        cur ^= 1;
    }

    #pragma unroll
    for (int j = 0; j < NJ; ++j) {
        const int col = n0 + wc + j * 16 + l15;
        const float bcol = bias[col];
        #pragma unroll
        for (int i = 0; i < 2; ++i) {
            if (z == vt_z) {
                const int row0 = m0 + wr + i * 16 + quad * 4;
                const int bb = row0 >> 11, s0 = row0 & 2047;
                u16x4 t;
                #pragma unroll
                for (int r = 0; r < 4; ++r) t[r] = f2bf((acc[i][j][r] + bcol) * scale);
                *(u16x4*)&((u16*)C)[((size_t)bb * E_ + col) * S_ + s0] = t;
            } else {
                #pragma unroll
                for (int r = 0; r < 4; ++r) {
                    const int row = m0 + wr + i * 16 + quad * 4 + r;
                    const float v = (acc[i][j][r] + bcol) * scale;
                    if (c_f32) ((float*)C)[(size_t)row * 1024 + col] = v;
                    else       ((u16*)C)[(size_t)row * 1024 + col]  = f2bf(v);
                }
            }
        }
    }
}

// ---------------------------------------------------------------------------
// Flash attention v9 (proven 62.7-63.7 us, frozen): T12 machinery (swapped
// QK^T, rho-permute, permlane32_swap P-build, ballot mask, no Sb, 0 bank
// conflicts), 4 waves x 2 q-strips.
// ---------------------------------------------------------------------------
__global__ __launch_bounds__(256, 2)
void attn_v9(const u16* __restrict__ Q, const u16* __restrict__ K,
             const u16* __restrict__ Vt_g, const int* __restrict__ mask,
             u16* __restrict__ ctx)
{
    __shared__ alignas(16) u16 Ks[2][64 * 64];
    __shared__ alignas(16) u16 Vs[2][64 * 64];

    const int tid  = threadIdx.x;
    const int lane = tid & 63;
    const int wv   = tid >> 6;      // 0..3
    const int l15  = lane & 15;
    const int quad = lane >> 4;
    const int sw   = l15 & 7;
    const int qt = blockIdx.x;
    const int bh = blockIdx.y;
    const int b  = bh >> 4, h = bh & 15;

    const size_t qk_off = (size_t)b * S_ * E_ + (size_t)h * DH_;
    const size_t vt_off = ((size_t)b * E_ + (size_t)h * DH_) * S_;

    const int qr0 = qt * 128 + wv * 16 + l15;
    const int qr1 = qr0 + 64;
    const bf16x8 qa0 = ldfrag(&Q[qk_off + (size_t)qr0 * E_ + quad * 8]);
    const bf16x8 qa1 = ldfrag(&Q[qk_off + (size_t)qr0 * E_ + 32 + quad * 8]);
    const bf16x8 qb0 = ldfrag(&Q[qk_off + (size_t)qr1 * E_ + quad * 8]);
    const bf16x8 qb1 = ldfrag(&Q[qk_off + (size_t)qr1 * E_ + 32 + quad * 8]);

    u16x8 ou;
    #pragma unroll
    for (int j = 0; j < 8; ++j) ou[j] = 0x3F80;    // bf16 1.0
    const bf16x8 ones = __builtin_bit_cast(bf16x8, ou);

    f32x4 oaccA[4] = {}, oaccB[4] = {};
    f32x4 laccA = {}, laccB = {};

    // rho: swap bits 2,3 of l15 -> K-row permutation for kf load.
    // Output quad q then holds keys 16t + 4*pi(q), pi = (0,2,1,3).
    const int rho = (l15 & 3) | ((l15 & 4) << 1) | ((l15 & 8) >> 1);
    const int swr = rho & 7;                          // XOR-swizzle key for rho'd row
    const int s0q = 4 * (((quad & 1) << 1) | (quad >> 1));  // 4*pi(quad)

    const int srow = tid >> 3;        // 0..31 (256 threads)
    const int sp   = tid & 7;         // position block
    const int sg   = sp ^ (srow & 7); // global col block (XOR placement swz)

    // stage one 64-key chunk (2 gld16/thread per matrix)
    auto stage = [&](int kc, int buf) {
        #pragma unroll
        for (int g = 0; g < 2; ++g) {
            const int r = g * 32 + srow;
            gld16(&K[qk_off + (size_t)(kc + r) * E_ + sg * 8],
                  &Ks[buf][r * 64 + sp * 8]);
            gld16(&Vt_g[vt_off + (size_t)r * S_ + kc + sg * 8],
                  &Vs[buf][r * 64 + sp * 8]);
        }
    };

    stage(0, 0);
    int cur = 0;

    for (int kc = 0; kc < S_; kc += 64) {
        __syncthreads();                 // drains gld16s -> buf[cur] ready
        if (kc + 64 < S_) stage(kc + 64, cur ^ 1);   // prefetch next chunk

        // key-validity bitmask for this chunk (bit L = mask[kc+L])
        const uint64_t bm = __ballot(mask[b * S_ + kc + lane] != 0);
        const uint32_t mq0 = (uint32_t)(bm >> s0q);          // t = 0,1
        const uint32_t mq1 = (uint32_t)(bm >> (s0q + 32));   // t = 2,3

        // S^T = K Q^T per 16-key strip; kf pair shared by both q-strips.
        uint32_t cwA[4][2], cwB[4][2];   // [t][u]: bf16 pair at k=16t+s0q+2u
        #pragma unroll
        for (int t = 0; t < 4; ++t) {
            const int R = t * 16 + rho;
            bf16x8 kf0 = ldfrag(&Ks[cur][R * 64 + (quad ^ swr) * 8]);
            bf16x8 kf1 = ldfrag(&Ks[cur][R * 64 + ((4 + quad) ^ swr) * 8]);
            f32x4 sA = {}, sB = {};
            sA = __builtin_amdgcn_mfma_f32_16x16x32_bf16(kf0, qa0, sA, 0, 0, 0);
            sA = __builtin_amdgcn_mfma_f32_16x16x32_bf16(kf1, qa1, sA, 0, 0, 0);
            sB = __builtin_amdgcn_mfma_f32_16x16x32_bf16(kf0, qb0, sB, 0, 0, 0);
            sB = __builtin_amdgcn_mfma_f32_16x16x32_bf16(kf1, qb1, sB, 0, 0, 0);
            const uint32_t mb = (t < 2) ? mq0 : mq1;
            const int tb = (t & 1) << 4;
            const bool v0 = (mb >> (tb + 0)) & 1u;
            const bool v1 = (mb >> (tb + 1)) & 1u;
            const bool v2 = (mb >> (tb + 2)) & 1u;
            const bool v3 = (mb >> (tb + 3)) & 1u;
            cwA[t][0] = pkbf(v0 ? __expf(sA[0]) : 0.0f, v1 ? __expf(sA[1]) : 0.0f);
            cwA[t][1] = pkbf(v2 ? __expf(sA[2]) : 0.0f, v3 ? __expf(sA[3]) : 0.0f);
            cwB[t][0] = pkbf(v0 ? __expf(sB[0]) : 0.0f, v1 ? __expf(sB[1]) : 0.0f);
            cwB[t][1] = pkbf(v2 ? __expf(sB[2]) : 0.0f, v3 ? __expf(sB[3]) : 0.0f);
        }

        // quad redistribution: 4 permlane32_swaps per strip build A-frags.
        // swap(a,b): a' = {a.lo, b.lo}, b' = {a.hi, b.hi}
        uint32_t a00 = cwA[0][0], a02 = cwA[1][0];
        asm("v_permlane32_swap_b32 %0, %1" : "+v"(a00), "+v"(a02));
        uint32_t a01 = cwA[0][1], a03 = cwA[1][1];
        asm("v_permlane32_swap_b32 %0, %1" : "+v"(a01), "+v"(a03));
        uint32_t a10 = cwA[2][0], a12 = cwA[3][0];
        asm("v_permlane32_swap_b32 %0, %1" : "+v"(a10), "+v"(a12));
        uint32_t a11 = cwA[2][1], a13 = cwA[3][1];
        asm("v_permlane32_swap_b32 %0, %1" : "+v"(a11), "+v"(a13));
        uint32_t b00 = cwB[0][0], b02 = cwB[1][0];
        asm("v_permlane32_swap_b32 %0, %1" : "+v"(b00), "+v"(b02));
        uint32_t b01 = cwB[0][1], b03 = cwB[1][1];
        asm("v_permlane32_swap_b32 %0, %1" : "+v"(b01), "+v"(b03));
        uint32_t b10 = cwB[2][0], b12 = cwB[3][0];
        asm("v_permlane32_swap_b32 %0, %1" : "+v"(b10), "+v"(b12));
        uint32_t b11 = cwB[2][1], b13 = cwB[3][1];
        asm("v_permlane32_swap_b32 %0, %1" : "+v"(b11), "+v"(b13));
        u32x4 WA0; WA0[0] = a00; WA0[1] = a01; WA0[2] = a02; WA0[3] = a03;
        u32x4 WA1; WA1[0] = a10; WA1[1] = a11; WA1[2] = a12; WA1[3] = a13;
        u32x4 WB0; WB0[0] = b00; WB0[1] = b01; WB0[2] = b02; WB0[3] = b03;
        u32x4 WB1; WB1[0] = b10; WB1[1] = b11; WB1[2] = b12; WB1[3] = b13;
        const bf16x8 paA0 = __builtin_bit_cast(bf16x8, WA0);
        const bf16x8 paA1 = __builtin_bit_cast(bf16x8, WA1);
        const bf16x8 paB0 = __builtin_bit_cast(bf16x8, WB0);
        const bf16x8 paB1 = __builtin_bit_cast(bf16x8, WB1);

        // O += P @ V ; l += P @ ones  (vb pair shared by both strips)
        #pragma unroll
        for (int c = 0; c < 4; ++c) {
            const int D = c * 16 + l15;
            bf16x8 vb0 = ldfrag(&Vs[cur][D * 64 + (quad ^ sw) * 8]);
            bf16x8 vb1 = ldfrag(&Vs[cur][D * 64 + ((4 + quad) ^ sw) * 8]);
            oaccA[c] = __builtin_amdgcn_mfma_f32_16x16x32_bf16(paA0, vb0, oaccA[c], 0, 0, 0);
            oaccA[c] = __builtin_amdgcn_mfma_f32_16x16x32_bf16(paA1, vb1, oaccA[c], 0, 0, 0);
            oaccB[c] = __builtin_amdgcn_mfma_f32_16x16x32_bf16(paB0, vb0, oaccB[c], 0, 0, 0);
            oaccB[c] = __builtin_amdgcn_mfma_f32_16x16x32_bf16(paB1, vb1, oaccB[c], 0, 0, 0);
        }
        laccA = __builtin_amdgcn_mfma_f32_16x16x32_bf16(paA0, ones, laccA, 0, 0, 0);
        laccA = __builtin_amdgcn_mfma_f32_16x16x32_bf16(paA1, ones, laccA, 0, 0, 0);
        laccB = __builtin_amdgcn_mfma_f32_16x16x32_bf16(paB0, ones, laccB, 0, 0, 0);
        laccB = __builtin_amdgcn_mfma_f32_16x16x32_bf16(paB1, ones, laccB, 0, 0, 0);
        cur ^= 1;
    }

    #pragma unroll
    for (int c = 0; c < 4; ++c) {
        const int e = h * DH_ + c * 16 + l15;
        #pragma unroll
        for (int r = 0; r < 4; ++r) {
            const int qgA = qt * 128 + wv * 16 + quad * 4 + r;
            ctx[((size_t)b * S_ + qgA) * E_ + e] = f2bf(oaccA[c][r] / laccA[r]);
            const int qgB = qgA + 64;
            ctx[((size_t)b * S_ + qgB) * E_ + e] = f2bf(oaccB[c][r] / laccB[r]);
        }
    }
}

// ---------------------------------------------------------------------------
// Fallback tier kernels (r6/r7, proven, unchanged)
// ---------------------------------------------------------------------------
__global__ __launch_bounds__(256)
void gemm_bias(const void* __restrict__ A, int a_f32,
               const float* __restrict__ W, const float* __restrict__ bias,
               void* __restrict__ C, int c_f32,
               int M, int N, int K, float scale)
{
    __shared__ alignas(16) u16 As[64 * 32];
    __shared__ alignas(16) u16 Wt[64 * 32];
    const int tid  = threadIdx.x;
    const int lane = tid & 63;
    const int wv   = tid >> 6;
    const int l15  = lane & 15;
    const int quad = lane >> 4;
    const int m0 = blockIdx.y * 64, n0 = blockIdx.x * 64;
    const int wr = (wv >> 1) * 32, wc = (wv & 1) * 32;
    const int ar = tid >> 2, ac = (tid & 3) * 8;
    const int wk = tid >> 3, wn = (tid & 7) * 8;
    f32x4 acc[2][2] = {};
    for (int k0 = 0; k0 < K; k0 += 32) {
        __syncthreads();
        if (a_f32) {
            const float* Af = (const float*)A;
            const float* p = &Af[(size_t)(m0 + ar) * K + k0 + ac];
            float4 f0 = *(const float4*)p; float4 f1 = *(const float4*)(p + 4);
            u16x8 t;
            t[0] = f2bf(f0.x); t[1] = f2bf(f0.y); t[2] = f2bf(f0.z); t[3] = f2bf(f0.w);
            t[4] = f2bf(f1.x); t[5] = f2bf(f1.y); t[6] = f2bf(f1.z); t[7] = f2bf(f1.w);
            *(u16x8*)&As[ar * 32 + ac] = t;
        } else {
            const u16* Ab = (const u16*)A;
            *(u16x8*)&As[ar * 32 + ac] = *(const u16x8*)&Ab[(size_t)(m0 + ar) * K + k0 + ac];
        }
        {
            const float* p = &W[(size_t)(k0 + wk) * N + n0 + wn];
            float4 g0 = *(const float4*)p; float4 g1 = *(const float4*)(p + 4);
            float fv[8] = {g0.x, g0.y, g0.z, g0.w, g1.x, g1.y, g1.z, g1.w};
            #pragma unroll
            for (int j = 0; j < 8; ++j) Wt[(wn + j) * 32 + wk] = f2bf(fv[j]);
        }
        __syncthreads();
        bf16x8 a[2], b[2];
        #pragma unroll
        for (int sm = 0; sm < 2; ++sm) a[sm] = ldfrag(&As[(wr + sm * 16 + l15) * 32 + quad * 8]);
        #pragma unroll
        for (int sn = 0; sn < 2; ++sn) b[sn] = ldfrag(&Wt[(wc + sn * 16 + l15) * 32 + quad * 8]);
        #pragma unroll
        for (int sm = 0; sm < 2; ++sm)
            #pragma unroll
            for (int sn = 0; sn < 2; ++sn)
                acc[sm][sn] = __builtin_amdgcn_mfma_f32_16x16x32_bf16(a[sm], b[sn], acc[sm][sn], 0, 0, 0);
    }
    #pragma unroll
    for (int sm = 0; sm < 2; ++sm)
        #pragma unroll
        for (int sn = 0; sn < 2; ++sn) {
            const int col = n0 + wc + sn * 16 + l15;
            const float bcol = bias[col];
            #pragma unroll
            for (int r = 0; r < 4; ++r) {
                const int row = m0 + wr + sm * 16 + quad * 4 + r;
                const float v = (acc[sm][sn][r] + bcol) * scale;
                if (c_f32) ((float*)C)[(size_t)row * N + col] = v;
                else       ((u16*)C)[(size_t)row * N + col]  = f2bf(v);
            }
        }
}

__global__ __launch_bounds__(256)
void attn_v2(const u16* __restrict__ Q, const u16* __restrict__ K,
             const u16* __restrict__ V, const int* __restrict__ mask,
             u16* __restrict__ ctx, int BH_per_B)
{
    __shared__ alignas(16) u16 Ks[64 * 72];
    __shared__ alignas(16) u16 Vt[64 * 72];
    __shared__ alignas(16) u16 Pb[4][16 * 72];
    const int tid  = threadIdx.x;
    const int lane = tid & 63;
    const int wv   = tid >> 6;
    const int l15  = lane & 15;
    const int quad = lane >> 4;
    const int qt = blockIdx.x;
    const int bh = blockIdx.y;
    const int b  = bh / BH_per_B, h = bh % BH_per_B;
    const size_t headoff = (size_t)b * S_ * E_ + (size_t)h * DH_;
    const int qrow = qt * 64 + wv * 16 + l15;
    const bf16x8 qf0 = ldfrag(&Q[headoff + (size_t)qrow * E_ + quad * 8]);
    const bf16x8 qf1 = ldfrag(&Q[headoff + (size_t)qrow * E_ + 32 + quad * 8]);
    f32x4 oacc[4] = {};
    float mrun[4] = {-1e30f, -1e30f, -1e30f, -1e30f};
    float lrun[4] = {0.f, 0.f, 0.f, 0.f};
    const int skey = tid >> 2;
    const int sd0  = (tid & 3) * 16;
    for (int kc = 0; kc < S_; kc += 64) {
        __syncthreads();
        {
            const u16* kg = &K[headoff + (size_t)(kc + skey) * E_ + sd0];
            *(u16x8*)&Ks[skey * 72 + sd0]     = *(const u16x8*)kg;
            *(u16x8*)&Ks[skey * 72 + sd0 + 8] = *(const u16x8*)(kg + 8);
            const u16* vg = &V[headoff + (size_t)(kc + skey) * E_ + sd0];
            u16x8 v0 = *(const u16x8*)vg;
            u16x8 v1 = *(const u16x8*)(vg + 8);
            #pragma unroll
            for (int j = 0; j < 8; ++j) {
                const int d = sd0 + j;
                Vt[d * 72 + (skey ^ (((d >> 3) & 7) * 8))] = v0[j];
            }
            #pragma unroll
            for (int j = 0; j < 8; ++j) {
                const int d = sd0 + 8 + j;
                Vt[d * 72 + (skey ^ (((d >> 3) & 7) * 8))] = v1[j];
            }
        }
        __syncthreads();
        f32x4 sb[4];
        #pragma unroll
        for (int t = 0; t < 4; ++t) {
            bf16x8 kf0 = ldfrag(&Ks[(t * 16 + l15) * 72 + quad * 8]);
            bf16x8 kf1 = ldfrag(&Ks[(t * 16 + l15) * 72 + 32 + quad * 8]);
            f32x4 s = {};
            s = __builtin_amdgcn_mfma_f32_16x16x32_bf16(qf0, kf0, s, 0, 0, 0);
            s = __builtin_amdgcn_mfma_f32_16x16x32_bf16(qf1, kf1, s, 0, 0, 0);
            const int mv = mask[b * S_ + kc + t * 16 + l15];
            #pragma unroll
            for (int r = 0; r < 4; ++r) sb[t][r] = (mv == 0) ? -1e9f : s[r];
        }
        #pragma unroll
        for (int r = 0; r < 4; ++r) {
            float m = fmaxf(fmaxf(sb[0][r], sb[1][r]), fmaxf(sb[2][r], sb[3][r]));
            #pragma unroll
            for (int off = 1; off < 16; off <<= 1) m = fmaxf(m, __shfl_xor(m, off));
            const float mnew  = fmaxf(mrun[r], m);
            const float alpha = __expf(mrun[r] - mnew);
            mrun[r] = mnew;
            float sum = 0.f;
            #pragma unroll
            for (int t = 0; t < 4; ++t) {
                const float p = __expf(sb[t][r] - mnew);
                sb[t][r] = p; sum += p;
            }
            #pragma unroll
            for (int off = 1; off < 16; off <<= 1) sum += __shfl_xor(sum, off);
            lrun[r] = lrun[r] * alpha + sum;
            #pragma unroll
            for (int c = 0; c < 4; ++c) oacc[c][r] *= alpha;
        }
        #pragma unroll
        for (int t = 0; t < 4; ++t)
            #pragma unroll
            for (int r = 0; r < 4; ++r)
                Pb[wv][(quad * 4 + r) * 72 + t * 16 + l15] = f2bf(sb[t][r]);
        const bf16x8 pa0 = ldfrag(&Pb[wv][l15 * 72 + quad * 8]);
        const bf16x8 pa1 = ldfrag(&Pb[wv][l15 * 72 + 32 + quad * 8]);
        #pragma unroll
        for (int c = 0; c < 4; ++c) {
            const int d = c * 16 + l15;
            const int sg = ((d >> 3) & 7) * 8;
            bf16x8 vb0 = ldfrag(&Vt[d * 72 + ((quad * 8) ^ sg)]);
            bf16x8 vb1 = ldfrag(&Vt[d * 72 + ((32 + quad * 8) ^ sg)]);
            oacc[c] = __builtin_amdgcn_mfma_f32_16x16x32_bf16(pa0, vb0, oacc[c], 0, 0, 0);
            oacc[c] = __builtin_amdgcn_mfma_f32_16x16x32_bf16(pa1, vb1, oacc[c], 0, 0, 0);
        }
    }
    #pragma unroll
    for (int c = 0; c < 4; ++c) {
        const int e = h * DH_ + c * 16 + l15;
        #pragma unroll
        for (int r = 0; r < 4; ++r) {
            const int qg = qt * 64 + wv * 16 + quad * 4 + r;
            ctx[((size_t)b * S_ + qg) * E_ + e] = f2bf(oacc[c][r] / lrun[r]);
        }
    }
}

// ---------------------------------------------------------------------------
extern "C" void kernel_launch(void* const* d_in, const int* in_sizes, int n_in,
                              void* d_out, int out_size, void* d_ws, size_t ws_size,
                              hipStream_t stream)
{
    const float* query = (const float*)d_in[0];
    const float* key   = (const float*)d_in[1];
    const float* value = (const float*)d_in[2];
    const int*   mask  = (const int*)d_in[3];
    const float* Wq = (const float*)d_in[4];  const float* bq = (const float*)d_in[5];
    const float* Wk = (const float*)d_in[6];  const float* bk = (const float*)d_in[7];
    const float* Wv = (const float*)d_in[8];  const float* bv = (const float*)d_in[9];
    const float* Wo = (const float*)d_in[10]; const float* bo = (const float*)d_in[11];
    float* out = (float*)d_out;

    u16* ws = (u16*)d_ws;
    dim3 blk(256);
    dim3 blk512(512);

    const size_t need_fancy = (size_t)(6 * MELEMS + 4 * WE) * sizeof(u16);  // 56 MB
    const size_t need_full  = (size_t)(4 * MELEMS) * sizeof(u16) + 64;      // 33.6 MB

    if (ws_size >= need_fancy) {
        u16* Cp  = ws;                 // attn output (bf16); qkv bf16 slots unused
        u16* Wqt = ws + 3 * MELEMS;
        u16* Wkt = Wqt + WE;
        u16* Wvt = Wkt + WE;
        u16* Wot = Wvt + WE;
        u16* Qp  = Wot + WE;
        u16* Kp  = Qp + MELEMS;
        u16* Vp  = Kp + MELEMS;        // holds V^T [B][E][S]

        cvt_w<<<dim3(1024), blk, 0, stream>>>(Wq, Wk, Wv, Wo,
                                              Wqt, Wkt, Wvt, Wot);

        gemm_qkv_f<<<dim3(16, 32, 3), blk512, 0, stream>>>(
            query, key, value, Wqt, Wkt, Wvt, bq, bk, bv,
            Qp, Kp, Vp, /*vt_z=*/2, 0.125f);

        attn_v9<<<dim3(S_ / 128, B_ * H_), dim3(256), 0, stream>>>(Qp, Kp, Vp, mask, Cp);

        gemm_bt64<64><<<dim3(16, 32, 1), blk512, 0, stream>>>(
            Cp, Cp, Cp, Wot, Wot, Wot, bo, bo, bo,
            out, out, out, 1, /*vt_z=*/-1, 1.0f, E_);
    } else if (ws_size >= need_full) {
        u16* Qp = ws;
        u16* Kp = ws + MELEMS;
        u16* Vp = ws + 2 * MELEMS;
        u16* Cp = ws + 3 * MELEMS;
        const int M = B_ * S_;
        dim3 gg(E_ / 64, M / 64);
        gemm_bias<<<gg, blk, 0, stream>>>(query, 1, Wq, bq, Qp, 0, M, E_, E_, 0.125f);
        gemm_bias<<<gg, blk, 0, stream>>>(key,   1, Wk, bk, Kp, 0, M, E_, E_, 1.0f);
        gemm_bias<<<gg, blk, 0, stream>>>(value, 1, Wv, bv, Vp, 0, M, E_, E_, 1.0f);
        attn_v2<<<dim3(S_ / 64, B_ * H_), blk, 0, stream>>>(Qp, Kp, Vp, mask, Cp, H_);
        gemm_bias<<<gg, blk, 0, stream>>>(Cp, 0, Wo, bo, out, 1, M, E_, E_, 1.0f);
    } else {
        const size_t szb = (size_t)S_ * E_;
        u16* Qp = ws; u16* Kp = ws + szb; u16* Vp = ws + 2 * szb; u16* Cp = ws + 3 * szb;
        dim3 gg(E_ / 64, S_ / 64);
        for (int b = 0; b < B_; ++b) {
            gemm_bias<<<gg, blk, 0, stream>>>(query + b * szb, 1, Wq, bq, Qp, 0, S_, E_, E_, 0.125f);
            gemm_bias<<<gg, blk, 0, stream>>>(key   + b * szb, 1, Wk, bk, Kp, 0, S_, E_, E_, 1.0f);
            gemm_bias<<<gg, blk, 0, stream>>>(value + b * szb, 1, Wv, bv, Vp, 0, S_, E_, E_, 1.0f);
            attn_v2<<<dim3(S_ / 64, H_), blk, 0, stream>>>(Qp, Kp, Vp, mask + b * S_, Cp, H_);
            gemm_bias<<<gg, blk, 0, stream>>>(Cp, 0, Wo, bo, ((float*)d_out) + b * szb, 1, S_, E_, E_, 1.0f);
        }
    }
}

// Round 13
// 229.134 us; speedup vs baseline: 1.1384x; 1.1384x over previous
//
#include <hip/hip_runtime.h>
#include <hip/hip_bf16.h>
#include <stdint.h>

#define B_ 2
#define S_ 2048
#define E_ 1024
#define H_ 16
#define DH_ 64
#define MELEMS (4096 * 1024)   // B*S*E
#define WE (1024 * 1024)

typedef unsigned short u16;
typedef __bf16 bf16x8 __attribute__((ext_vector_type(8)));
typedef u16 u16x8 __attribute__((ext_vector_type(8)));
typedef u16 u16x4 __attribute__((ext_vector_type(4)));
typedef float f32x4 __attribute__((ext_vector_type(4)));
typedef uint32_t u32x4 __attribute__((ext_vector_type(4)));

__device__ __forceinline__ float bf2f(u16 u) {
    union { uint32_t i; float f; } v; v.i = ((uint32_t)u) << 16; return v.f;
}
__device__ __forceinline__ u16 f2bf(float f) {   // RNE fp32->bf16
    union { float f; uint32_t i; } v; v.f = f;
    uint32_t r = (v.i + 0x7FFFu + ((v.i >> 16) & 1u)) >> 16;
    return (u16)r;
}
__device__ __forceinline__ uint32_t pkbf(float a, float b) {  // packed cvt
    __hip_bfloat162 h = __float22bfloat162_rn(make_float2(a, b));
    uint32_t r; __builtin_memcpy(&r, &h, 4);   // bit_cast rejected: not TC
    return r;
}
__device__ __forceinline__ bf16x8 ldfrag(const u16* p) {
    u16x8 t = *(const u16x8*)p;
    return __builtin_bit_cast(bf16x8, t);
}
__device__ __forceinline__ void gld16(const void* g, void* l) {
    __builtin_amdgcn_global_load_lds(
        (const __attribute__((address_space(1))) void*)g,
        (__attribute__((address_space(3))) void*)l, 16, 0, 0);
}

// ---------------------------------------------------------------------------
// Merged convert: blocks 0..6143 = fp32->bf16 of q/k/v; 6144..7167 = weight
// transpose W[K][N] fp32 -> Wt[N][K] bf16 (LDS-tiled, 65-stride).
// (R11-proven; fp32-A fused-GEMM alternative rejected twice: R7 locality,
// R12 reg-staging latency.)
// ---------------------------------------------------------------------------
__global__ __launch_bounds__(256)
void cvt_all(const float* __restrict__ q, const float* __restrict__ k,
             const float* __restrict__ v,
             const float* __restrict__ W0, const float* __restrict__ W1,
             const float* __restrict__ W2, const float* __restrict__ W3,
             u16* __restrict__ Qi, u16* __restrict__ Ki, u16* __restrict__ Vi,
             u16* __restrict__ T0, u16* __restrict__ T1,
             u16* __restrict__ T2, u16* __restrict__ T3)
{
    __shared__ float tile[64][65];
    const int bid = blockIdx.x;
    const int tid = threadIdx.x;

    if (bid < 6144) {
        const int z = bid >> 11;            // /2048
        const int cx = bid & 2047;
        const float* src = (z == 0) ? q : (z == 1) ? k : v;
        u16* dst = (z == 0) ? Qi : (z == 1) ? Ki : Vi;
        const size_t i8 = ((size_t)cx * 256 + tid) * 8;
        float4 f0 = *(const float4*)&src[i8];
        float4 f1 = *(const float4*)&src[i8 + 4];
        u16x8 t;
        t[0] = f2bf(f0.x); t[1] = f2bf(f0.y); t[2] = f2bf(f0.z); t[3] = f2bf(f0.w);
        t[4] = f2bf(f1.x); t[5] = f2bf(f1.y); t[6] = f2bf(f1.z); t[7] = f2bf(f1.w);
        *(u16x8*)&dst[i8] = t;
    } else {
        const int rr = bid - 6144;          // 0..1023
        const int z = rr >> 8;
        const int tt = rr & 255;
        const float* W = (z == 0) ? W0 : (z == 1) ? W1 : (z == 2) ? W2 : W3;
        u16* T = (z == 0) ? T0 : (z == 1) ? T1 : (z == 2) ? T2 : T3;
        const int n0 = (tt & 15) * 64, k0 = (tt >> 4) * 64;
        const int r = tid >> 2, c0 = (tid & 3) * 16;

        #pragma unroll
        for (int i = 0; i < 4; ++i) {
            float4 w = *(const float4*)&W[(size_t)(k0 + r) * 1024 + n0 + c0 + i * 4];
            tile[r][c0 + i * 4 + 0] = w.x; tile[r][c0 + i * 4 + 1] = w.y;
            tile[r][c0 + i * 4 + 2] = w.z; tile[r][c0 + i * 4 + 3] = w.w;
        }
        __syncthreads();
        u16x8 a, b;
        #pragma unroll
        for (int j = 0; j < 8; ++j) a[j] = f2bf(tile[c0 + j][r]);
        #pragma unroll
        for (int j = 0; j < 8; ++j) b[j] = f2bf(tile[c0 + 8 + j][r]);
        *(u16x8*)&T[(size_t)(n0 + r) * 1024 + k0 + c0] = a;
        *(u16x8*)&T[(size_t)(n0 + r) * 1024 + k0 + c0 + 8] = b;
    }
}

// ---------------------------------------------------------------------------
// gemm_bt64 (R11-proven best): 512 threads / 8 waves, BK=64, T2 XOR swizzle,
// T1 XCD-chunk, dbuf prefetch-next-then-compute. BN=64: LDS 48 KB ->
// 3 blocks/CU capacity; __launch_bounds__(512,6).
// ---------------------------------------------------------------------------
template<int BN>
__global__ __launch_bounds__(512, 6)
void gemm_bt64(const u16* __restrict__ A0, const u16* __restrict__ A1,
               const u16* __restrict__ A2,
               const u16* __restrict__ Bt0, const u16* __restrict__ Bt1,
               const u16* __restrict__ Bt2,
               const float* __restrict__ b0, const float* __restrict__ b1,
               const float* __restrict__ b2,
               void* __restrict__ C0, void* __restrict__ C1, void* __restrict__ C2,
               int c_f32, int vt_z, float scale0, int K)
{
    const int z = blockIdx.z;
    const u16* A  = (z == 0) ? A0 : (z == 1) ? A1 : A2;
    const u16* Bt = (z == 0) ? Bt0 : (z == 1) ? Bt1 : Bt2;
    const float* bias = (z == 0) ? b0 : (z == 1) ? b1 : b2;
    void* C = (z == 0) ? C0 : (z == 1) ? C1 : C2;
    const float scale = (z == 0) ? scale0 : 1.0f;

    __shared__ alignas(16) u16 As[2][128 * 64];
    __shared__ alignas(16) u16 Bs[2][BN * 64];

    const int tid  = threadIdx.x;
    const int lane = tid & 63;
    const int wv   = tid >> 6;       // 0..7
    const int l15  = lane & 15;
    const int quad = lane >> 4;

    // --- T1 XCD-chunked swizzle (bijective; nwg%8==0 by launch config) ---
    const int nwg = gridDim.x * gridDim.y;
    const int hw  = blockIdx.x + gridDim.x * blockIdx.y;
    const int cpx = nwg >> 3;
    const int lg  = (hw & 7) * cpx + (hw >> 3);
    const int bx  = lg % gridDim.x;
    const int by  = lg / gridDim.x;

    const int m0 = by * 128;
    const int n0 = bx * BN;
    const int wr = (wv >> 1) * 32;          // 4 row-quarters of 32
    const int wc = (wv & 1) * (BN / 2);     // 2 col-halves

    const int srow8 = tid >> 3;      // 0..63
    const int sp    = tid & 7;       // 16B col-block within 64-col row

    constexpr int NJ = BN / 32;
    f32x4 acc[2][NJ] = {};

    auto stage = [&](int k0, int buf) {
        #pragma unroll
        for (int g = 0; g < 2; ++g) {           // A: 128 rows, 64 rows/round
            const int r = g * 64 + srow8;
            const int sg = sp ^ (r & 7);
            gld16(&A[(size_t)(m0 + r) * K + k0 + sg * 8],
                  &As[buf][r * 64 + sp * 8]);
        }
        #pragma unroll
        for (int g = 0; g < BN / 64; ++g) {     // B: BN rows
            const int r = g * 64 + srow8;
            const int sg = sp ^ (r & 7);
            gld16(&Bt[(size_t)(n0 + r) * K + k0 + sg * 8],
                  &Bs[buf][r * 64 + sp * 8]);
        }
    };

    stage(0, 0);
    int cur = 0;

    for (int k0 = 0; k0 < K; k0 += 64) {
        __syncthreads();                         // drains gld16 -> buf[cur] ready
        if (k0 + 64 < K) stage(k0 + 64, cur ^ 1);  // prefetch next K-tile

        #pragma unroll
        for (int kk = 0; kk < 2; ++kk) {
            bf16x8 a[2], b[NJ];
            #pragma unroll
            for (int i = 0; i < 2; ++i) {
                const int R = wr + i * 16 + l15;
                a[i] = ldfrag(&As[cur][R * 64 + (((kk * 4 + quad) ^ (R & 7)) * 8)]);
            }
            #pragma unroll
            for (int j = 0; j < NJ; ++j) {
                const int R = wc + j * 16 + l15;
                b[j] = ldfrag(&Bs[cur][R * 64 + (((kk * 4 + quad) ^ (R & 7)) * 8)]);
            }
            #pragma unroll
            for (int i = 0; i < 2; ++i)
                #pragma unroll
                for (int j = 0; j < NJ; ++j)
                    acc[i][j] = __builtin_amdgcn_mfma_f32_16x16x32_bf16(
                        a[i], b[j], acc[i][j], 0, 0, 0);
        }
        cur ^= 1;
    }

    #pragma unroll
    for (int j = 0; j < NJ; ++j) {
        const int col = n0 + wc + j * 16 + l15;
        const float bcol = bias[col];
        #pragma unroll
        for (int i = 0; i < 2; ++i) {
            if (z == vt_z) {
                const int row0 = m0 + wr + i * 16 + quad * 4;
                const int bb = row0 >> 11, s0 = row0 & 2047;
                u16x4 t;
                #pragma unroll
                for (int r = 0; r < 4; ++r) t[r] = f2bf((acc[i][j][r] + bcol) * scale);
                *(u16x4*)&((u16*)C)[((size_t)bb * E_ + col) * S_ + s0] = t;
            } else {
                #pragma unroll
                for (int r = 0; r < 4; ++r) {
                    const int row = m0 + wr + i * 16 + quad * 4 + r;
                    const float v = (acc[i][j][r] + bcol) * scale;
                    if (c_f32) ((float*)C)[(size_t)row * 1024 + col] = v;
                    else       ((u16*)C)[(size_t)row * 1024 + col]  = f2bf(v);
                }
            }
        }
    }
}

// ---------------------------------------------------------------------------
// Flash attention v9 (proven 62.7-63.7 us, frozen): T12 machinery (swapped
// QK^T, rho-permute, permlane32_swap P-build, ballot mask, no Sb, 0 bank
// conflicts), 4 waves x 2 q-strips.
// ---------------------------------------------------------------------------
__global__ __launch_bounds__(256, 2)
void attn_v9(const u16* __restrict__ Q, const u16* __restrict__ K,
             const u16* __restrict__ Vt_g, const int* __restrict__ mask,
             u16* __restrict__ ctx)
{
    __shared__ alignas(16) u16 Ks[2][64 * 64];
    __shared__ alignas(16) u16 Vs[2][64 * 64];

    const int tid  = threadIdx.x;
    const int lane = tid & 63;
    const int wv   = tid >> 6;      // 0..3
    const int l15  = lane & 15;
    const int quad = lane >> 4;
    const int sw   = l15 & 7;
    const int qt = blockIdx.x;
    const int bh = blockIdx.y;
    const int b  = bh >> 4, h = bh & 15;

    const size_t qk_off = (size_t)b * S_ * E_ + (size_t)h * DH_;
    const size_t vt_off = ((size_t)b * E_ + (size_t)h * DH_) * S_;

    const int qr0 = qt * 128 + wv * 16 + l15;
    const int qr1 = qr0 + 64;
    const bf16x8 qa0 = ldfrag(&Q[qk_off + (size_t)qr0 * E_ + quad * 8]);
    const bf16x8 qa1 = ldfrag(&Q[qk_off + (size_t)qr0 * E_ + 32 + quad * 8]);
    const bf16x8 qb0 = ldfrag(&Q[qk_off + (size_t)qr1 * E_ + quad * 8]);
    const bf16x8 qb1 = ldfrag(&Q[qk_off + (size_t)qr1 * E_ + 32 + quad * 8]);

    u16x8 ou;
    #pragma unroll
    for (int j = 0; j < 8; ++j) ou[j] = 0x3F80;    // bf16 1.0
    const bf16x8 ones = __builtin_bit_cast(bf16x8, ou);

    f32x4 oaccA[4] = {}, oaccB[4] = {};
    f32x4 laccA = {}, laccB = {};

    // rho: swap bits 2,3 of l15 -> K-row permutation for kf load.
    // Output quad q then holds keys 16t + 4*pi(q), pi = (0,2,1,3).
    const int rho = (l15 & 3) | ((l15 & 4) << 1) | ((l15 & 8) >> 1);
    const int swr = rho & 7;                          // XOR-swizzle key for rho'd row
    const int s0q = 4 * (((quad & 1) << 1) | (quad >> 1));  // 4*pi(quad)

    const int srow = tid >> 3;        // 0..31 (256 threads)
    const int sp   = tid & 7;         // position block
    const int sg   = sp ^ (srow & 7); // global col block (XOR placement swz)

    // stage one 64-key chunk (2 gld16/thread per matrix)
    auto stage = [&](int kc, int buf) {
        #pragma unroll
        for (int g = 0; g < 2; ++g) {
            const int r = g * 32 + srow;
            gld16(&K[qk_off + (size_t)(kc + r) * E_ + sg * 8],
                  &Ks[buf][r * 64 + sp * 8]);
            gld16(&Vt_g[vt_off + (size_t)r * S_ + kc + sg * 8],
                  &Vs[buf][r * 64 + sp * 8]);
        }
    };

    stage(0, 0);
    int cur = 0;

    for (int kc = 0; kc < S_; kc += 64) {
        __syncthreads();                 // drains gld16s -> buf[cur] ready
        if (kc + 64 < S_) stage(kc + 64, cur ^ 1);   // prefetch next chunk

        // key-validity bitmask for this chunk (bit L = mask[kc+L])
        const uint64_t bm = __ballot(mask[b * S_ + kc + lane] != 0);
        const uint32_t mq0 = (uint32_t)(bm >> s0q);          // t = 0,1
        const uint32_t mq1 = (uint32_t)(bm >> (s0q + 32));   // t = 2,3

        // S^T = K Q^T per 16-key strip; kf pair shared by both q-strips.
        uint32_t cwA[4][2], cwB[4][2];   // [t][u]: bf16 pair at k=16t+s0q+2u
        #pragma unroll
        for (int t = 0; t < 4; ++t) {
            const int R = t * 16 + rho;
            bf16x8 kf0 = ldfrag(&Ks[cur][R * 64 + (quad ^ swr) * 8]);
            bf16x8 kf1 = ldfrag(&Ks[cur][R * 64 + ((4 + quad) ^ swr) * 8]);
            f32x4 sA = {}, sB = {};
            sA = __builtin_amdgcn_mfma_f32_16x16x32_bf16(kf0, qa0, sA, 0, 0, 0);
            sA = __builtin_amdgcn_mfma_f32_16x16x32_bf16(kf1, qa1, sA, 0, 0, 0);
            sB = __builtin_amdgcn_mfma_f32_16x16x32_bf16(kf0, qb0, sB, 0, 0, 0);
            sB = __builtin_amdgcn_mfma_f32_16x16x32_bf16(kf1, qb1, sB, 0, 0, 0);
            const uint32_t mb = (t < 2) ? mq0 : mq1;
            const int tb = (t & 1) << 4;
            const bool v0 = (mb >> (tb + 0)) & 1u;
            const bool v1 = (mb >> (tb + 1)) & 1u;
            const bool v2 = (mb >> (tb + 2)) & 1u;
            const bool v3 = (mb >> (tb + 3)) & 1u;
            cwA[t][0] = pkbf(v0 ? __expf(sA[0]) : 0.0f, v1 ? __expf(sA[1]) : 0.0f);
            cwA[t][1] = pkbf(v2 ? __expf(sA[2]) : 0.0f, v3 ? __expf(sA[3]) : 0.0f);
            cwB[t][0] = pkbf(v0 ? __expf(sB[0]) : 0.0f, v1 ? __expf(sB[1]) : 0.0f);
            cwB[t][1] = pkbf(v2 ? __expf(sB[2]) : 0.0f, v3 ? __expf(sB[3]) : 0.0f);
        }

        // quad redistribution: 4 permlane32_swaps per strip build A-frags.
        // swap(a,b): a' = {a.lo, b.lo}, b' = {a.hi, b.hi}
        uint32_t a00 = cwA[0][0], a02 = cwA[1][0];
        asm("v_permlane32_swap_b32 %0, %1" : "+v"(a00), "+v"(a02));
        uint32_t a01 = cwA[0][1], a03 = cwA[1][1];
        asm("v_permlane32_swap_b32 %0, %1" : "+v"(a01), "+v"(a03));
        uint32_t a10 = cwA[2][0], a12 = cwA[3][0];
        asm("v_permlane32_swap_b32 %0, %1" : "+v"(a10), "+v"(a12));
        uint32_t a11 = cwA[2][1], a13 = cwA[3][1];
        asm("v_permlane32_swap_b32 %0, %1" : "+v"(a11), "+v"(a13));
        uint32_t b00 = cwB[0][0], b02 = cwB[1][0];
        asm("v_permlane32_swap_b32 %0, %1" : "+v"(b00), "+v"(b02));
        uint32_t b01 = cwB[0][1], b03 = cwB[1][1];
        asm("v_permlane32_swap_b32 %0, %1" : "+v"(b01), "+v"(b03));
        uint32_t b10 = cwB[2][0], b12 = cwB[3][0];
        asm("v_permlane32_swap_b32 %0, %1" : "+v"(b10), "+v"(b12));
        uint32_t b11 = cwB[2][1], b13 = cwB[3][1];
        asm("v_permlane32_swap_b32 %0, %1" : "+v"(b11), "+v"(b13));
        u32x4 WA0; WA0[0] = a00; WA0[1] = a01; WA0[2] = a02; WA0[3] = a03;
        u32x4 WA1; WA1[0] = a10; WA1[1] = a11; WA1[2] = a12; WA1[3] = a13;
        u32x4 WB0; WB0[0] = b00; WB0[1] = b01; WB0[2] = b02; WB0[3] = b03;
        u32x4 WB1; WB1[0] = b10; WB1[1] = b11; WB1[2] = b12; WB1[3] = b13;
        const bf16x8 paA0 = __builtin_bit_cast(bf16x8, WA0);
        const bf16x8 paA1 = __builtin_bit_cast(bf16x8, WA1);
        const bf16x8 paB0 = __builtin_bit_cast(bf16x8, WB0);
        const bf16x8 paB1 = __builtin_bit_cast(bf16x8, WB1);

        // O += P @ V ; l += P @ ones  (vb pair shared by both strips)
        #pragma unroll
        for (int c = 0; c < 4; ++c) {
            const int D = c * 16 + l15;
            bf16x8 vb0 = ldfrag(&Vs[cur][D * 64 + (quad ^ sw) * 8]);
            bf16x8 vb1 = ldfrag(&Vs[cur][D * 64 + ((4 + quad) ^ sw) * 8]);
            oaccA[c] = __builtin_amdgcn_mfma_f32_16x16x32_bf16(paA0, vb0, oaccA[c], 0, 0, 0);
            oaccA[c] = __builtin_amdgcn_mfma_f32_16x16x32_bf16(paA1, vb1, oaccA[c], 0, 0, 0);
            oaccB[c] = __builtin_amdgcn_mfma_f32_16x16x32_bf16(paB0, vb0, oaccB[c], 0, 0, 0);
            oaccB[c] = __builtin_amdgcn_mfma_f32_16x16x32_bf16(paB1, vb1, oaccB[c], 0, 0, 0);
        }
        laccA = __builtin_amdgcn_mfma_f32_16x16x32_bf16(paA0, ones, laccA, 0, 0, 0);
        laccA = __builtin_amdgcn_mfma_f32_16x16x32_bf16(paA1, ones, laccA, 0, 0, 0);
        laccB = __builtin_amdgcn_mfma_f32_16x16x32_bf16(paB0, ones, laccB, 0, 0, 0);
        laccB = __builtin_amdgcn_mfma_f32_16x16x32_bf16(paB1, ones, laccB, 0, 0, 0);
        cur ^= 1;
    }

    #pragma unroll
    for (int c = 0; c < 4; ++c) {
        const int e = h * DH_ + c * 16 + l15;
        #pragma unroll
        for (int r = 0; r < 4; ++r) {
            const int qgA = qt * 128 + wv * 16 + quad * 4 + r;
            ctx[((size_t)b * S_ + qgA) * E_ + e] = f2bf(oaccA[c][r] / laccA[r]);
            const int qgB = qgA + 64;
            ctx[((size_t)b * S_ + qgB) * E_ + e] = f2bf(oaccB[c][r] / laccB[r]);
        }
    }
}

// ---------------------------------------------------------------------------
// Fallback tier kernels (r6/r7, proven, unchanged)
// ---------------------------------------------------------------------------
__global__ __launch_bounds__(256)
void gemm_bias(const void* __restrict__ A, int a_f32,
               const float* __restrict__ W, const float* __restrict__ bias,
               void* __restrict__ C, int c_f32,
               int M, int N, int K, float scale)
{
    __shared__ alignas(16) u16 As[64 * 32];
    __shared__ alignas(16) u16 Wt[64 * 32];
    const int tid  = threadIdx.x;
    const int lane = tid & 63;
    const int wv   = tid >> 6;
    const int l15  = lane & 15;
    const int quad = lane >> 4;
    const int m0 = blockIdx.y * 64, n0 = blockIdx.x * 64;
    const int wr = (wv >> 1) * 32, wc = (wv & 1) * 32;
    const int ar = tid >> 2, ac = (tid & 3) * 8;
    const int wk = tid >> 3, wn = (tid & 7) * 8;
    f32x4 acc[2][2] = {};
    for (int k0 = 0; k0 < K; k0 += 32) {
        __syncthreads();
        if (a_f32) {
            const float* Af = (const float*)A;
            const float* p = &Af[(size_t)(m0 + ar) * K + k0 + ac];
            float4 f0 = *(const float4*)p; float4 f1 = *(const float4*)(p + 4);
            u16x8 t;
            t[0] = f2bf(f0.x); t[1] = f2bf(f0.y); t[2] = f2bf(f0.z); t[3] = f2bf(f0.w);
            t[4] = f2bf(f1.x); t[5] = f2bf(f1.y); t[6] = f2bf(f1.z); t[7] = f2bf(f1.w);
            *(u16x8*)&As[ar * 32 + ac] = t;
        } else {
            const u16* Ab = (const u16*)A;
            *(u16x8*)&As[ar * 32 + ac] = *(const u16x8*)&Ab[(size_t)(m0 + ar) * K + k0 + ac];
        }
        {
            const float* p = &W[(size_t)(k0 + wk) * N + n0 + wn];
            float4 g0 = *(const float4*)p; float4 g1 = *(const float4*)(p + 4);
            float fv[8] = {g0.x, g0.y, g0.z, g0.w, g1.x, g1.y, g1.z, g1.w};
            #pragma unroll
            for (int j = 0; j < 8; ++j) Wt[(wn + j) * 32 + wk] = f2bf(fv[j]);
        }
        __syncthreads();
        bf16x8 a[2], b[2];
        #pragma unroll
        for (int sm = 0; sm < 2; ++sm) a[sm] = ldfrag(&As[(wr + sm * 16 + l15) * 32 + quad * 8]);
        #pragma unroll
        for (int sn = 0; sn < 2; ++sn) b[sn] = ldfrag(&Wt[(wc + sn * 16 + l15) * 32 + quad * 8]);
        #pragma unroll
        for (int sm = 0; sm < 2; ++sm)
            #pragma unroll
            for (int sn = 0; sn < 2; ++sn)
                acc[sm][sn] = __builtin_amdgcn_mfma_f32_16x16x32_bf16(a[sm], b[sn], acc[sm][sn], 0, 0, 0);
    }
    #pragma unroll
    for (int sm = 0; sm < 2; ++sm)
        #pragma unroll
        for (int sn = 0; sn < 2; ++sn) {
            const int col = n0 + wc + sn * 16 + l15;
            const float bcol = bias[col];
            #pragma unroll
            for (int r = 0; r < 4; ++r) {
                const int row = m0 + wr + sm * 16 + quad * 4 + r;
                const float v = (acc[sm][sn][r] + bcol) * scale;
                if (c_f32) ((float*)C)[(size_t)row * N + col] = v;
                else       ((u16*)C)[(size_t)row * N + col]  = f2bf(v);
            }
        }
}

__global__ __launch_bounds__(256)
void attn_v2(const u16* __restrict__ Q, const u16* __restrict__ K,
             const u16* __restrict__ V, const int* __restrict__ mask,
             u16* __restrict__ ctx, int BH_per_B)
{
    __shared__ alignas(16) u16 Ks[64 * 72];
    __shared__ alignas(16) u16 Vt[64 * 72];
    __shared__ alignas(16) u16 Pb[4][16 * 72];
    const int tid  = threadIdx.x;
    const int lane = tid & 63;
    const int wv   = tid >> 6;
    const int l15  = lane & 15;
    const int quad = lane >> 4;
    const int qt = blockIdx.x;
    const int bh = blockIdx.y;
    const int b  = bh / BH_per_B, h = bh % BH_per_B;
    const size_t headoff = (size_t)b * S_ * E_ + (size_t)h * DH_;
    const int qrow = qt * 64 + wv * 16 + l15;
    const bf16x8 qf0 = ldfrag(&Q[headoff + (size_t)qrow * E_ + quad * 8]);
    const bf16x8 qf1 = ldfrag(&Q[headoff + (size_t)qrow * E_ + 32 + quad * 8]);
    f32x4 oacc[4] = {};
    float mrun[4] = {-1e30f, -1e30f, -1e30f, -1e30f};
    float lrun[4] = {0.f, 0.f, 0.f, 0.f};
    const int skey = tid >> 2;
    const int sd0  = (tid & 3) * 16;
    for (int kc = 0; kc < S_; kc += 64) {
        __syncthreads();
        {
            const u16* kg = &K[headoff + (size_t)(kc + skey) * E_ + sd0];
            *(u16x8*)&Ks[skey * 72 + sd0]     = *(const u16x8*)kg;
            *(u16x8*)&Ks[skey * 72 + sd0 + 8] = *(const u16x8*)(kg + 8);
            const u16* vg = &V[headoff + (size_t)(kc + skey) * E_ + sd0];
            u16x8 v0 = *(const u16x8*)vg;
            u16x8 v1 = *(const u16x8*)(vg + 8);
            #pragma unroll
            for (int j = 0; j < 8; ++j) {
                const int d = sd0 + j;
                Vt[d * 72 + (skey ^ (((d >> 3) & 7) * 8))] = v0[j];
            }
            #pragma unroll
            for (int j = 0; j < 8; ++j) {
                const int d = sd0 + 8 + j;
                Vt[d * 72 + (skey ^ (((d >> 3) & 7) * 8))] = v1[j];
            }
        }
        __syncthreads();
        f32x4 sb[4];
        #pragma unroll
        for (int t = 0; t < 4; ++t) {
            bf16x8 kf0 = ldfrag(&Ks[(t * 16 + l15) * 72 + quad * 8]);
            bf16x8 kf1 = ldfrag(&Ks[(t * 16 + l15) * 72 + 32 + quad * 8]);
            f32x4 s = {};
            s = __builtin_amdgcn_mfma_f32_16x16x32_bf16(qf0, kf0, s, 0, 0, 0);
            s = __builtin_amdgcn_mfma_f32_16x16x32_bf16(qf1, kf1, s, 0, 0, 0);
            const int mv = mask[b * S_ + kc + t * 16 + l15];
            #pragma unroll
            for (int r = 0; r < 4; ++r) sb[t][r] = (mv == 0) ? -1e9f : s[r];
        }
        #pragma unroll
        for (int r = 0; r < 4; ++r) {
            float m = fmaxf(fmaxf(sb[0][r], sb[1][r]), fmaxf(sb[2][r], sb[3][r]));
            #pragma unroll
            for (int off = 1; off < 16; off <<= 1) m = fmaxf(m, __shfl_xor(m, off));
            const float mnew  = fmaxf(mrun[r], m);
            const float alpha = __expf(mrun[r] - mnew);
            mrun[r] = mnew;
            float sum = 0.f;
            #pragma unroll
            for (int t = 0; t < 4; ++t) {
                const float p = __expf(sb[t][r] - mnew);
                sb[t][r] = p; sum += p;
            }
            #pragma unroll
            for (int off = 1; off < 16; off <<= 1) sum += __shfl_xor(sum, off);
            lrun[r] = lrun[r] * alpha + sum;
            #pragma unroll
            for (int c = 0; c < 4; ++c) oacc[c][r] *= alpha;
        }
        #pragma unroll
        for (int t = 0; t < 4; ++t)
            #pragma unroll
            for (int r = 0; r < 4; ++r)
                Pb[wv][(quad * 4 + r) * 72 + t * 16 + l15] = f2bf(sb[t][r]);
        const bf16x8 pa0 = ldfrag(&Pb[wv][l15 * 72 + quad * 8]);
        const bf16x8 pa1 = ldfrag(&Pb[wv][l15 * 72 + 32 + quad * 8]);
        #pragma unroll
        for (int c = 0; c < 4; ++c) {
            const int d = c * 16 + l15;
            const int sg = ((d >> 3) & 7) * 8;
            bf16x8 vb0 = ldfrag(&Vt[d * 72 + ((quad * 8) ^ sg)]);
            bf16x8 vb1 = ldfrag(&Vt[d * 72 + ((32 + quad * 8) ^ sg)]);
            oacc[c] = __builtin_amdgcn_mfma_f32_16x16x32_bf16(pa0, vb0, oacc[c], 0, 0, 0);
            oacc[c] = __builtin_amdgcn_mfma_f32_16x16x32_bf16(pa1, vb1, oacc[c], 0, 0, 0);
        }
    }
    #pragma unroll
    for (int c = 0; c < 4; ++c) {
        const int e = h * DH_ + c * 16 + l15;
        #pragma unroll
        for (int r = 0; r < 4; ++r) {
            const int qg = qt * 64 + wv * 16 + quad * 4 + r;
            ctx[((size_t)b * S_ + qg) * E_ + e] = f2bf(oacc[c][r] / lrun[r]);
        }
    }
}

// ---------------------------------------------------------------------------
extern "C" void kernel_launch(void* const* d_in, const int* in_sizes, int n_in,
                              void* d_out, int out_size, void* d_ws, size_t ws_size,
                              hipStream_t stream)
{
    const float* query = (const float*)d_in[0];
    const float* key   = (const float*)d_in[1];
    const float* value = (const float*)d_in[2];
    const int*   mask  = (const int*)d_in[3];
    const float* Wq = (const float*)d_in[4];  const float* bq = (const float*)d_in[5];
    const float* Wk = (const float*)d_in[6];  const float* bk = (const float*)d_in[7];
    const float* Wv = (const float*)d_in[8];  const float* bv = (const float*)d_in[9];
    const float* Wo = (const float*)d_in[10]; const float* bo = (const float*)d_in[11];
    float* out = (float*)d_out;

    u16* ws = (u16*)d_ws;
    dim3 blk(256);
    dim3 blk512(512);

    const size_t need_fancy = (size_t)(6 * MELEMS + 4 * WE) * sizeof(u16);  // 56 MB
    const size_t need_full  = (size_t)(4 * MELEMS) * sizeof(u16) + 64;      // 33.6 MB

    if (ws_size >= need_fancy) {
        u16* Qi  = ws;
        u16* Ki  = Qi + MELEMS;
        u16* Vi  = Ki + MELEMS;
        u16* Wqt = Vi + MELEMS;
        u16* Wkt = Wqt + WE;
        u16* Wvt = Wkt + WE;
        u16* Wot = Wvt + WE;
        u16* Qp  = Wot + WE;
        u16* Kp  = Qp + MELEMS;
        u16* Vp  = Kp + MELEMS;   // holds V^T [B][E][S]
        u16* Cp  = Qi;            // alias: Qi/Ki/Vi dead after QKV GEMMs

        cvt_all<<<dim3(7168), blk, 0, stream>>>(query, key, value,
                                                Wq, Wk, Wv, Wo,
                                                Qi, Ki, Vi, Wqt, Wkt, Wvt, Wot);

        gemm_bt64<64><<<dim3(16, 32, 3), blk512, 0, stream>>>(
            Qi, Ki, Vi, Wqt, Wkt, Wvt, bq, bk, bv,
            Qp, Kp, Vp, 0, /*vt_z=*/2, 0.125f, E_);

        attn_v9<<<dim3(S_ / 128, B_ * H_), dim3(256), 0, stream>>>(Qp, Kp, Vp, mask, Cp);

        gemm_bt64<64><<<dim3(16, 32, 1), blk512, 0, stream>>>(
            Cp, Cp, Cp, Wot, Wot, Wot, bo, bo, bo,
            out, out, out, 1, /*vt_z=*/-1, 1.0f, E_);
    } else if (ws_size >= need_full) {
        u16* Qp = ws;
        u16* Kp = ws + MELEMS;
        u16* Vp = ws + 2 * MELEMS;
        u16* Cp = ws + 3 * MELEMS;
        const int M = B_ * S_;
        dim3 gg(E_ / 64, M / 64);
        gemm_bias<<<gg, blk, 0, stream>>>(query, 1, Wq, bq, Qp, 0, M, E_, E_, 0.125f);
        gemm_bias<<<gg, blk, 0, stream>>>(key,   1, Wk, bk, Kp, 0, M, E_, E_, 1.0f);
        gemm_bias<<<gg, blk, 0, stream>>>(value, 1, Wv, bv, Vp, 0, M, E_, E_, 1.0f);
        attn_v2<<<dim3(S_ / 64, B_ * H_), blk, 0, stream>>>(Qp, Kp, Vp, mask, Cp, H_);
        gemm_bias<<<gg, blk, 0, stream>>>(Cp, 0, Wo, bo, out, 1, M, E_, E_, 1.0f);
    } else {
        const size_t szb = (size_t)S_ * E_;
        u16* Qp = ws; u16* Kp = ws + szb; u16* Vp = ws + 2 * szb; u16* Cp = ws + 3 * szb;
        dim3 gg(E_ / 64, S_ / 64);
        for (int b = 0; b < B_; ++b) {
            gemm_bias<<<gg, blk, 0, stream>>>(query + b * szb, 1, Wq, bq, Qp, 0, S_, E_, E_, 0.125f);
            gemm_bias<<<gg, blk, 0, stream>>>(key   + b * szb, 1, Wk, bk, Kp, 0, S_, E_, E_, 1.0f);
            gemm_bias<<<gg, blk, 0, stream>>>(value + b * szb, 1, Wv, bv, Vp, 0, S_, E_, E_, 1.0f);
            attn_v2<<<dim3(S_ / 64, H_), blk, 0, stream>>>(Qp, Kp, Vp, mask + b * S_, Cp, H_);
            gemm_bias<<<gg, blk, 0, stream>>>(Cp, 0, Wo, bo, ((float*)d_out) + b * szb, 1, S_, E_, E_, 1.0f);
        }
    }
}

// Round 14
// 228.283 us; speedup vs baseline: 1.1427x; 1.0037x over previous
//
#include <hip/hip_runtime.h>
#include <hip/hip_bf16.h>
#include <stdint.h>

#define B_ 2
#define S_ 2048
#define E_ 1024
#define H_ 16
#define DH_ 64
#define MELEMS (4096 * 1024)   // B*S*E
#define WE (1024 * 1024)

typedef unsigned short u16;
typedef __bf16 bf16x8 __attribute__((ext_vector_type(8)));
typedef u16 u16x8 __attribute__((ext_vector_type(8)));
typedef u16 u16x4 __attribute__((ext_vector_type(4)));
typedef float f32x4 __attribute__((ext_vector_type(4)));
typedef uint32_t u32x4 __attribute__((ext_vector_type(4)));

__device__ __forceinline__ float bf2f(u16 u) {
    union { uint32_t i; float f; } v; v.i = ((uint32_t)u) << 16; return v.f;
}
__device__ __forceinline__ u16 f2bf(float f) {   // RNE fp32->bf16
    union { float f; uint32_t i; } v; v.f = f;
    uint32_t r = (v.i + 0x7FFFu + ((v.i >> 16) & 1u)) >> 16;
    return (u16)r;
}
__device__ __forceinline__ uint32_t pkbf(float a, float b) {  // packed cvt
    __hip_bfloat162 h = __float22bfloat162_rn(make_float2(a, b));
    uint32_t r; __builtin_memcpy(&r, &h, 4);   // bit_cast rejected: not TC
    return r;
}
__device__ __forceinline__ bf16x8 ldfrag(const u16* p) {
    u16x8 t = *(const u16x8*)p;
    return __builtin_bit_cast(bf16x8, t);
}
__device__ __forceinline__ void gld16(const void* g, void* l) {
    __builtin_amdgcn_global_load_lds(
        (const __attribute__((address_space(1))) void*)g,
        (__attribute__((address_space(3))) void*)l, 16, 0, 0);
}

// ---------------------------------------------------------------------------
// Merged convert: blocks 0..6143 = fp32->bf16 of q/k/v; 6144..7167 = weight
// transpose W[K][N] fp32 -> Wt[N][K] bf16 (LDS-tiled, 65-stride).
// ---------------------------------------------------------------------------
__global__ __launch_bounds__(256)
void cvt_all(const float* __restrict__ q, const float* __restrict__ k,
             const float* __restrict__ v,
             const float* __restrict__ W0, const float* __restrict__ W1,
             const float* __restrict__ W2, const float* __restrict__ W3,
             u16* __restrict__ Qi, u16* __restrict__ Ki, u16* __restrict__ Vi,
             u16* __restrict__ T0, u16* __restrict__ T1,
             u16* __restrict__ T2, u16* __restrict__ T3)
{
    __shared__ float tile[64][65];
    const int bid = blockIdx.x;
    const int tid = threadIdx.x;

    if (bid < 6144) {
        const int z = bid >> 11;            // /2048
        const int cx = bid & 2047;
        const float* src = (z == 0) ? q : (z == 1) ? k : v;
        u16* dst = (z == 0) ? Qi : (z == 1) ? Ki : Vi;
        const size_t i8 = ((size_t)cx * 256 + tid) * 8;
        float4 f0 = *(const float4*)&src[i8];
        float4 f1 = *(const float4*)&src[i8 + 4];
        u16x8 t;
        t[0] = f2bf(f0.x); t[1] = f2bf(f0.y); t[2] = f2bf(f0.z); t[3] = f2bf(f0.w);
        t[4] = f2bf(f1.x); t[5] = f2bf(f1.y); t[6] = f2bf(f1.z); t[7] = f2bf(f1.w);
        *(u16x8*)&dst[i8] = t;
    } else {
        const int rr = bid - 6144;          // 0..1023
        const int z = rr >> 8;
        const int tt = rr & 255;
        const float* W = (z == 0) ? W0 : (z == 1) ? W1 : (z == 2) ? W2 : W3;
        u16* T = (z == 0) ? T0 : (z == 1) ? T1 : (z == 2) ? T2 : T3;
        const int n0 = (tt & 15) * 64, k0 = (tt >> 4) * 64;
        const int r = tid >> 2, c0 = (tid & 3) * 16;

        #pragma unroll
        for (int i = 0; i < 4; ++i) {
            float4 w = *(const float4*)&W[(size_t)(k0 + r) * 1024 + n0 + c0 + i * 4];
            tile[r][c0 + i * 4 + 0] = w.x; tile[r][c0 + i * 4 + 1] = w.y;
            tile[r][c0 + i * 4 + 2] = w.z; tile[r][c0 + i * 4 + 3] = w.w;
        }
        __syncthreads();
        u16x8 a, b;
        #pragma unroll
        for (int j = 0; j < 8; ++j) a[j] = f2bf(tile[c0 + j][r]);
        #pragma unroll
        for (int j = 0; j < 8; ++j) b[j] = f2bf(tile[c0 + 8 + j][r]);
        *(u16x8*)&T[(size_t)(n0 + r) * 1024 + k0 + c0] = a;
        *(u16x8*)&T[(size_t)(n0 + r) * 1024 + k0 + c0 + 8] = b;
    }
}

// ---------------------------------------------------------------------------
// gemm_bt64 (R11-proven best): 512 threads / 8 waves, BK=64, T2 XOR swizzle,
// T1 XCD-chunk, dbuf prefetch-next-then-compute. BN=64: LDS 48 KB.
// ---------------------------------------------------------------------------
template<int BN>
__global__ __launch_bounds__(512, 6)
void gemm_bt64(const u16* __restrict__ A0, const u16* __restrict__ A1,
               const u16* __restrict__ A2,
               const u16* __restrict__ Bt0, const u16* __restrict__ Bt1,
               const u16* __restrict__ Bt2,
               const float* __restrict__ b0, const float* __restrict__ b1,
               const float* __restrict__ b2,
               void* __restrict__ C0, void* __restrict__ C1, void* __restrict__ C2,
               int c_f32, int vt_z, float scale0, int K)
{
    const int z = blockIdx.z;
    const u16* A  = (z == 0) ? A0 : (z == 1) ? A1 : A2;
    const u16* Bt = (z == 0) ? Bt0 : (z == 1) ? Bt1 : Bt2;
    const float* bias = (z == 0) ? b0 : (z == 1) ? b1 : b2;
    void* C = (z == 0) ? C0 : (z == 1) ? C1 : C2;
    const float scale = (z == 0) ? scale0 : 1.0f;

    __shared__ alignas(16) u16 As[2][128 * 64];
    __shared__ alignas(16) u16 Bs[2][BN * 64];

    const int tid  = threadIdx.x;
    const int lane = tid & 63;
    const int wv   = tid >> 6;       // 0..7
    const int l15  = lane & 15;
    const int quad = lane >> 4;

    // --- T1 XCD-chunked swizzle (bijective; nwg%8==0 by launch config) ---
    const int nwg = gridDim.x * gridDim.y;
    const int hw  = blockIdx.x + gridDim.x * blockIdx.y;
    const int cpx = nwg >> 3;
    const int lg  = (hw & 7) * cpx + (hw >> 3);
    const int bx  = lg % gridDim.x;
    const int by  = lg / gridDim.x;

    const int m0 = by * 128;
    const int n0 = bx * BN;
    const int wr = (wv >> 1) * 32;          // 4 row-quarters of 32
    const int wc = (wv & 1) * (BN / 2);     // 2 col-halves

    const int srow8 = tid >> 3;      // 0..63
    const int sp    = tid & 7;       // 16B col-block within 64-col row

    constexpr int NJ = BN / 32;
    f32x4 acc[2][NJ] = {};

    auto stage = [&](int k0, int buf) {
        #pragma unroll
        for (int g = 0; g < 2; ++g) {           // A: 128 rows, 64 rows/round
            const int r = g * 64 + srow8;
            const int sg = sp ^ (r & 7);
            gld16(&A[(size_t)(m0 + r) * K + k0 + sg * 8],
                  &As[buf][r * 64 + sp * 8]);
        }
        #pragma unroll
        for (int g = 0; g < BN / 64; ++g) {     // B: BN rows
            const int r = g * 64 + srow8;
            const int sg = sp ^ (r & 7);
            gld16(&Bt[(size_t)(n0 + r) * K + k0 + sg * 8],
                  &Bs[buf][r * 64 + sp * 8]);
        }
    };

    stage(0, 0);
    int cur = 0;

    for (int k0 = 0; k0 < K; k0 += 64) {
        __syncthreads();                         // drains gld16 -> buf[cur] ready
        if (k0 + 64 < K) stage(k0 + 64, cur ^ 1);  // prefetch next K-tile

        #pragma unroll
        for (int kk = 0; kk < 2; ++kk) {
            bf16x8 a[2], b[NJ];
            #pragma unroll
            for (int i = 0; i < 2; ++i) {
                const int R = wr + i * 16 + l15;
                a[i] = ldfrag(&As[cur][R * 64 + (((kk * 4 + quad) ^ (R & 7)) * 8)]);
            }
            #pragma unroll
            for (int j = 0; j < NJ; ++j) {
                const int R = wc + j * 16 + l15;
                b[j] = ldfrag(&Bs[cur][R * 64 + (((kk * 4 + quad) ^ (R & 7)) * 8)]);
            }
            #pragma unroll
            for (int i = 0; i < 2; ++i)
                #pragma unroll
                for (int j = 0; j < NJ; ++j)
                    acc[i][j] = __builtin_amdgcn_mfma_f32_16x16x32_bf16(
                        a[i], b[j], acc[i][j], 0, 0, 0);
        }
        cur ^= 1;
    }

    #pragma unroll
    for (int j = 0; j < NJ; ++j) {
        const int col = n0 + wc + j * 16 + l15;
        const float bcol = bias[col];
        #pragma unroll
        for (int i = 0; i < 2; ++i) {
            if (z == vt_z) {
                const int row0 = m0 + wr + i * 16 + quad * 4;
                const int bb = row0 >> 11, s0 = row0 & 2047;
                u16x4 t;
                #pragma unroll
                for (int r = 0; r < 4; ++r) t[r] = f2bf((acc[i][j][r] + bcol) * scale);
                *(u16x4*)&((u16*)C)[((size_t)bb * E_ + col) * S_ + s0] = t;
            } else {
                #pragma unroll
                for (int r = 0; r < 4; ++r) {
                    const int row = m0 + wr + i * 16 + quad * 4 + r;
                    const float v = (acc[i][j][r] + bcol) * scale;
                    if (c_f32) ((float*)C)[(size_t)row * 1024 + col] = v;
                    else       ((u16*)C)[(size_t)row * 1024 + col]  = f2bf(v);
                }
            }
        }
    }
}

// ---------------------------------------------------------------------------
// Flash attention v11 = v9 with KVBLK 64 -> 128, processed as two 64-key
// halves sharing ONE stage + ONE barrier per chunk. Same sync semantics
// (stage -> barrier -> compute, dbuf parity), same T12 machinery; barriers
// per block 32 -> 16, staged-load batches doubled, loop overhead halved.
// LDS 64 KB/block -> still 2 blocks/CU. V placement swizzle XORs low 3 bits
// of the 16-wide col-block with (d&7); the half bit (bit 3) is untouched,
// so reads address half h via h*8 + ((j*4+quad)^(D&7)). Math identical.
// ---------------------------------------------------------------------------
__global__ __launch_bounds__(256, 2)
void attn_v11(const u16* __restrict__ Q, const u16* __restrict__ K,
              const u16* __restrict__ Vt_g, const int* __restrict__ mask,
              u16* __restrict__ ctx)
{
    __shared__ alignas(16) u16 Ks[2][128 * 64];   // 128 key-rows x 64 d
    __shared__ alignas(16) u16 Vs[2][64 * 128];   // 64 d-rows x 128 keys

    const int tid  = threadIdx.x;
    const int lane = tid & 63;
    const int wv   = tid >> 6;      // 0..3
    const int l15  = lane & 15;
    const int quad = lane >> 4;
    const int sw   = l15 & 7;       // = D&7 for D = c*16+l15
    const int qt = blockIdx.x;
    const int bh = blockIdx.y;
    const int b  = bh >> 4, h = bh & 15;

    const size_t qk_off = (size_t)b * S_ * E_ + (size_t)h * DH_;
    const size_t vt_off = ((size_t)b * E_ + (size_t)h * DH_) * S_;

    const int qr0 = qt * 128 + wv * 16 + l15;
    const int qr1 = qr0 + 64;
    const bf16x8 qa0 = ldfrag(&Q[qk_off + (size_t)qr0 * E_ + quad * 8]);
    const bf16x8 qa1 = ldfrag(&Q[qk_off + (size_t)qr0 * E_ + 32 + quad * 8]);
    const bf16x8 qb0 = ldfrag(&Q[qk_off + (size_t)qr1 * E_ + quad * 8]);
    const bf16x8 qb1 = ldfrag(&Q[qk_off + (size_t)qr1 * E_ + 32 + quad * 8]);

    u16x8 ou;
    #pragma unroll
    for (int j = 0; j < 8; ++j) ou[j] = 0x3F80;    // bf16 1.0
    const bf16x8 ones = __builtin_bit_cast(bf16x8, ou);

    f32x4 oaccA[4] = {}, oaccB[4] = {};
    f32x4 laccA = {}, laccB = {};

    // rho: swap bits 2,3 of l15 -> K-row permutation for kf load.
    // Output quad q then holds keys 16t + 4*pi(q), pi = (0,2,1,3).
    const int rho = (l15 & 3) | ((l15 & 4) << 1) | ((l15 & 8) >> 1);
    const int swr = rho & 7;                          // XOR-swizzle key for rho'd row
    const int s0q = 4 * (((quad & 1) << 1) | (quad >> 1));  // 4*pi(quad)

    const int srow = tid >> 3;        // 0..31 (K staging)
    const int sp   = tid & 7;
    const int vrow = tid >> 4;        // 0..15 (V staging)
    const int vp   = tid & 15;        // 16B col-block within 128-key row

    // stage one 128-key chunk (4 gld16/thread per matrix).
    // K dest byte = base + lane*16 (r = g*32 + w*8 + (l>>3), sp = l&7).
    // V dest byte = base + lane*16 (d = g*16 + w*4 + (l>>4), vp = l&15).
    auto stage = [&](int kc, int buf) {
        #pragma unroll
        for (int g = 0; g < 4; ++g) {
            const int r = g * 32 + srow;           // key row 0..127
            const int sg = sp ^ (r & 7);
            gld16(&K[qk_off + (size_t)(kc + r) * E_ + sg * 8],
                  &Ks[buf][r * 64 + sp * 8]);
        }
        #pragma unroll
        for (int g = 0; g < 4; ++g) {
            const int d = g * 16 + vrow;           // d row 0..63
            const int cg = vp ^ (d & 7);           // global col-block (low-3 XOR)
            gld16(&Vt_g[vt_off + (size_t)d * S_ + kc + cg * 8],
                  &Vs[buf][d * 128 + vp * 8]);
        }
    };

    stage(0, 0);
    int cur = 0;

    for (int kc = 0; kc < S_; kc += 128) {
        __syncthreads();                 // drains gld16s -> buf[cur] ready
        if (kc + 128 < S_) stage(kc + 128, cur ^ 1);   // prefetch next chunk

        #pragma unroll
        for (int hh = 0; hh < 2; ++hh) {
            // key-validity bitmask for this 64-key half
            const uint64_t bm = __ballot(mask[b * S_ + kc + hh * 64 + lane] != 0);
            const uint32_t mq0 = (uint32_t)(bm >> s0q);          // t = 0,1
            const uint32_t mq1 = (uint32_t)(bm >> (s0q + 32));   // t = 2,3

            // S^T = K Q^T per 16-key strip; kf pair shared by both q-strips.
            uint32_t cwA[4][2], cwB[4][2];
            #pragma unroll
            for (int t = 0; t < 4; ++t) {
                const int R = hh * 64 + t * 16 + rho;   // (hh*64)&7==0 -> swr valid
                bf16x8 kf0 = ldfrag(&Ks[cur][R * 64 + (quad ^ swr) * 8]);
                bf16x8 kf1 = ldfrag(&Ks[cur][R * 64 + ((4 + quad) ^ swr) * 8]);
                f32x4 sA = {}, sB = {};
                sA = __builtin_amdgcn_mfma_f32_16x16x32_bf16(kf0, qa0, sA, 0, 0, 0);
                sA = __builtin_amdgcn_mfma_f32_16x16x32_bf16(kf1, qa1, sA, 0, 0, 0);
                sB = __builtin_amdgcn_mfma_f32_16x16x32_bf16(kf0, qb0, sB, 0, 0, 0);
                sB = __builtin_amdgcn_mfma_f32_16x16x32_bf16(kf1, qb1, sB, 0, 0, 0);
                const uint32_t mb = (t < 2) ? mq0 : mq1;
                const int tb = (t & 1) << 4;
                const bool v0 = (mb >> (tb + 0)) & 1u;
                const bool v1 = (mb >> (tb + 1)) & 1u;
                const bool v2 = (mb >> (tb + 2)) & 1u;
                const bool v3 = (mb >> (tb + 3)) & 1u;
                cwA[t][0] = pkbf(v0 ? __expf(sA[0]) : 0.0f, v1 ? __expf(sA[1]) : 0.0f);
                cwA[t][1] = pkbf(v2 ? __expf(sA[2]) : 0.0f, v3 ? __expf(sA[3]) : 0.0f);
                cwB[t][0] = pkbf(v0 ? __expf(sB[0]) : 0.0f, v1 ? __expf(sB[1]) : 0.0f);
                cwB[t][1] = pkbf(v2 ? __expf(sB[2]) : 0.0f, v3 ? __expf(sB[3]) : 0.0f);
            }

            // quad redistribution: 4 permlane32_swaps per strip build A-frags.
            uint32_t a00 = cwA[0][0], a02 = cwA[1][0];
            asm("v_permlane32_swap_b32 %0, %1" : "+v"(a00), "+v"(a02));
            uint32_t a01 = cwA[0][1], a03 = cwA[1][1];
            asm("v_permlane32_swap_b32 %0, %1" : "+v"(a01), "+v"(a03));
            uint32_t a10 = cwA[2][0], a12 = cwA[3][0];
            asm("v_permlane32_swap_b32 %0, %1" : "+v"(a10), "+v"(a12));
            uint32_t a11 = cwA[2][1], a13 = cwA[3][1];
            asm("v_permlane32_swap_b32 %0, %1" : "+v"(a11), "+v"(a13));
            uint32_t b00 = cwB[0][0], b02 = cwB[1][0];
            asm("v_permlane32_swap_b32 %0, %1" : "+v"(b00), "+v"(b02));
            uint32_t b01 = cwB[0][1], b03 = cwB[1][1];
            asm("v_permlane32_swap_b32 %0, %1" : "+v"(b01), "+v"(b03));
            uint32_t b10 = cwB[2][0], b12 = cwB[3][0];
            asm("v_permlane32_swap_b32 %0, %1" : "+v"(b10), "+v"(b12));
            uint32_t b11 = cwB[2][1], b13 = cwB[3][1];
            asm("v_permlane32_swap_b32 %0, %1" : "+v"(b11), "+v"(b13));
            u32x4 WA0; WA0[0] = a00; WA0[1] = a01; WA0[2] = a02; WA0[3] = a03;
            u32x4 WA1; WA1[0] = a10; WA1[1] = a11; WA1[2] = a12; WA1[3] = a13;
            u32x4 WB0; WB0[0] = b00; WB0[1] = b01; WB0[2] = b02; WB0[3] = b03;
            u32x4 WB1; WB1[0] = b10; WB1[1] = b11; WB1[2] = b12; WB1[3] = b13;
            const bf16x8 paA0 = __builtin_bit_cast(bf16x8, WA0);
            const bf16x8 paA1 = __builtin_bit_cast(bf16x8, WA1);
            const bf16x8 paB0 = __builtin_bit_cast(bf16x8, WB0);
            const bf16x8 paB1 = __builtin_bit_cast(bf16x8, WB1);

            // O += P @ V ; l += P @ ones  (vb pair shared by both strips)
            #pragma unroll
            for (int c = 0; c < 4; ++c) {
                const int D = c * 16 + l15;
                bf16x8 vb0 = ldfrag(&Vs[cur][D * 128 + ((hh * 8 + (quad ^ sw)) * 8)]);
                bf16x8 vb1 = ldfrag(&Vs[cur][D * 128 + ((hh * 8 + ((4 + quad) ^ sw)) * 8)]);
                oaccA[c] = __builtin_amdgcn_mfma_f32_16x16x32_bf16(paA0, vb0, oaccA[c], 0, 0, 0);
                oaccA[c] = __builtin_amdgcn_mfma_f32_16x16x32_bf16(paA1, vb1, oaccA[c], 0, 0, 0);
                oaccB[c] = __builtin_amdgcn_mfma_f32_16x16x32_bf16(paB0, vb0, oaccB[c], 0, 0, 0);
                oaccB[c] = __builtin_amdgcn_mfma_f32_16x16x32_bf16(paB1, vb1, oaccB[c], 0, 0, 0);
            }
            laccA = __builtin_amdgcn_mfma_f32_16x16x32_bf16(paA0, ones, laccA, 0, 0, 0);
            laccA = __builtin_amdgcn_mfma_f32_16x16x32_bf16(paA1, ones, laccA, 0, 0, 0);
            laccB = __builtin_amdgcn_mfma_f32_16x16x32_bf16(paB0, ones, laccB, 0, 0, 0);
            laccB = __builtin_amdgcn_mfma_f32_16x16x32_bf16(paB1, ones, laccB, 0, 0, 0);
        }
        cur ^= 1;
    }

    #pragma unroll
    for (int c = 0; c < 4; ++c) {
        const int e = h * DH_ + c * 16 + l15;
        #pragma unroll
        for (int r = 0; r < 4; ++r) {
            const int qgA = qt * 128 + wv * 16 + quad * 4 + r;
            ctx[((size_t)b * S_ + qgA) * E_ + e] = f2bf(oaccA[c][r] / laccA[r]);
            const int qgB = qgA + 64;
            ctx[((size_t)b * S_ + qgB) * E_ + e] = f2bf(oaccB[c][r] / laccB[r]);
        }
    }
}

// ---------------------------------------------------------------------------
// Fallback tier kernels (r6/r7, proven, unchanged)
// ---------------------------------------------------------------------------
__global__ __launch_bounds__(256)
void gemm_bias(const void* __restrict__ A, int a_f32,
               const float* __restrict__ W, const float* __restrict__ bias,
               void* __restrict__ C, int c_f32,
               int M, int N, int K, float scale)
{
    __shared__ alignas(16) u16 As[64 * 32];
    __shared__ alignas(16) u16 Wt[64 * 32];
    const int tid  = threadIdx.x;
    const int lane = tid & 63;
    const int wv   = tid >> 6;
    const int l15  = lane & 15;
    const int quad = lane >> 4;
    const int m0 = blockIdx.y * 64, n0 = blockIdx.x * 64;
    const int wr = (wv >> 1) * 32, wc = (wv & 1) * 32;
    const int ar = tid >> 2, ac = (tid & 3) * 8;
    const int wk = tid >> 3, wn = (tid & 7) * 8;
    f32x4 acc[2][2] = {};
    for (int k0 = 0; k0 < K; k0 += 32) {
        __syncthreads();
        if (a_f32) {
            const float* Af = (const float*)A;
            const float* p = &Af[(size_t)(m0 + ar) * K + k0 + ac];
            float4 f0 = *(const float4*)p; float4 f1 = *(const float4*)(p + 4);
            u16x8 t;
            t[0] = f2bf(f0.x); t[1] = f2bf(f0.y); t[2] = f2bf(f0.z); t[3] = f2bf(f0.w);
            t[4] = f2bf(f1.x); t[5] = f2bf(f1.y); t[6] = f2bf(f1.z); t[7] = f2bf(f1.w);
            *(u16x8*)&As[ar * 32 + ac] = t;
        } else {
            const u16* Ab = (const u16*)A;
            *(u16x8*)&As[ar * 32 + ac] = *(const u16x8*)&Ab[(size_t)(m0 + ar) * K + k0 + ac];
        }
        {
            const float* p = &W[(size_t)(k0 + wk) * N + n0 + wn];
            float4 g0 = *(const float4*)p; float4 g1 = *(const float4*)(p + 4);
            float fv[8] = {g0.x, g0.y, g0.z, g0.w, g1.x, g1.y, g1.z, g1.w};
            #pragma unroll
            for (int j = 0; j < 8; ++j) Wt[(wn + j) * 32 + wk] = f2bf(fv[j]);
        }
        __syncthreads();
        bf16x8 a[2], b[2];
        #pragma unroll
        for (int sm = 0; sm < 2; ++sm) a[sm] = ldfrag(&As[(wr + sm * 16 + l15) * 32 + quad * 8]);
        #pragma unroll
        for (int sn = 0; sn < 2; ++sn) b[sn] = ldfrag(&Wt[(wc + sn * 16 + l15) * 32 + quad * 8]);
        #pragma unroll
        for (int sm = 0; sm < 2; ++sm)
            #pragma unroll
            for (int sn = 0; sn < 2; ++sn)
                acc[sm][sn] = __builtin_amdgcn_mfma_f32_16x16x32_bf16(a[sm], b[sn], acc[sm][sn], 0, 0, 0);
    }
    #pragma unroll
    for (int sm = 0; sm < 2; ++sm)
        #pragma unroll
        for (int sn = 0; sn < 2; ++sn) {
            const int col = n0 + wc + sn * 16 + l15;
            const float bcol = bias[col];
            #pragma unroll
            for (int r = 0; r < 4; ++r) {
                const int row = m0 + wr + sm * 16 + quad * 4 + r;
                const float v = (acc[sm][sn][r] + bcol) * scale;
                if (c_f32) ((float*)C)[(size_t)row * N + col] = v;
                else       ((u16*)C)[(size_t)row * N + col]  = f2bf(v);
            }
        }
}

__global__ __launch_bounds__(256)
void attn_v2(const u16* __restrict__ Q, const u16* __restrict__ K,
             const u16* __restrict__ V, const int* __restrict__ mask,
             u16* __restrict__ ctx, int BH_per_B)
{
    __shared__ alignas(16) u16 Ks[64 * 72];
    __shared__ alignas(16) u16 Vt[64 * 72];
    __shared__ alignas(16) u16 Pb[4][16 * 72];
    const int tid  = threadIdx.x;
    const int lane = tid & 63;
    const int wv   = tid >> 6;
    const int l15  = lane & 15;
    const int quad = lane >> 4;
    const int qt = blockIdx.x;
    const int bh = blockIdx.y;
    const int b  = bh / BH_per_B, h = bh % BH_per_B;
    const size_t headoff = (size_t)b * S_ * E_ + (size_t)h * DH_;
    const int qrow = qt * 64 + wv * 16 + l15;
    const bf16x8 qf0 = ldfrag(&Q[headoff + (size_t)qrow * E_ + quad * 8]);
    const bf16x8 qf1 = ldfrag(&Q[headoff + (size_t)qrow * E_ + 32 + quad * 8]);
    f32x4 oacc[4] = {};
    float mrun[4] = {-1e30f, -1e30f, -1e30f, -1e30f};
    float lrun[4] = {0.f, 0.f, 0.f, 0.f};
    const int skey = tid >> 2;
    const int sd0  = (tid & 3) * 16;
    for (int kc = 0; kc < S_; kc += 64) {
        __syncthreads();
        {
            const u16* kg = &K[headoff + (size_t)(kc + skey) * E_ + sd0];
            *(u16x8*)&Ks[skey * 72 + sd0]     = *(const u16x8*)kg;
            *(u16x8*)&Ks[skey * 72 + sd0 + 8] = *(const u16x8*)(kg + 8);
            const u16* vg = &V[headoff + (size_t)(kc + skey) * E_ + sd0];
            u16x8 v0 = *(const u16x8*)vg;
            u16x8 v1 = *(const u16x8*)(vg + 8);
            #pragma unroll
            for (int j = 0; j < 8; ++j) {
                const int d = sd0 + j;
                Vt[d * 72 + (skey ^ (((d >> 3) & 7) * 8))] = v0[j];
            }
            #pragma unroll
            for (int j = 0; j < 8; ++j) {
                const int d = sd0 + 8 + j;
                Vt[d * 72 + (skey ^ (((d >> 3) & 7) * 8))] = v1[j];
            }
        }
        __syncthreads();
        f32x4 sb[4];
        #pragma unroll
        for (int t = 0; t < 4; ++t) {
            bf16x8 kf0 = ldfrag(&Ks[(t * 16 + l15) * 72 + quad * 8]);
            bf16x8 kf1 = ldfrag(&Ks[(t * 16 + l15) * 72 + 32 + quad * 8]);
            f32x4 s = {};
            s = __builtin_amdgcn_mfma_f32_16x16x32_bf16(qf0, kf0, s, 0, 0, 0);
            s = __builtin_amdgcn_mfma_f32_16x16x32_bf16(qf1, kf1, s, 0, 0, 0);
            const int mv = mask[b * S_ + kc + t * 16 + l15];
            #pragma unroll
            for (int r = 0; r < 4; ++r) sb[t][r] = (mv == 0) ? -1e9f : s[r];
        }
        #pragma unroll
        for (int r = 0; r < 4; ++r) {
            float m = fmaxf(fmaxf(sb[0][r], sb[1][r]), fmaxf(sb[2][r], sb[3][r]));
            #pragma unroll
            for (int off = 1; off < 16; off <<= 1) m = fmaxf(m, __shfl_xor(m, off));
            const float mnew  = fmaxf(mrun[r], m);
            const float alpha = __expf(mrun[r] - mnew);
            mrun[r] = mnew;
            float sum = 0.f;
            #pragma unroll
            for (int t = 0; t < 4; ++t) {
                const float p = __expf(sb[t][r] - mnew);
                sb[t][r] = p; sum += p;
            }
            #pragma unroll
            for (int off = 1; off < 16; off <<= 1) sum += __shfl_xor(sum, off);
            lrun[r] = lrun[r] * alpha + sum;
            #pragma unroll
            for (int c = 0; c < 4; ++c) oacc[c][r] *= alpha;
        }
        #pragma unroll
        for (int t = 0; t < 4; ++t)
            #pragma unroll
            for (int r = 0; r < 4; ++r)
                Pb[wv][(quad * 4 + r) * 72 + t * 16 + l15] = f2bf(sb[t][r]);
        const bf16x8 pa0 = ldfrag(&Pb[wv][l15 * 72 + quad * 8]);
        const bf16x8 pa1 = ldfrag(&Pb[wv][l15 * 72 + 32 + quad * 8]);
        #pragma unroll
        for (int c = 0; c < 4; ++c) {
            const int d = c * 16 + l15;
            const int sg = ((d >> 3) & 7) * 8;
            bf16x8 vb0 = ldfrag(&Vt[d * 72 + ((quad * 8) ^ sg)]);
            bf16x8 vb1 = ldfrag(&Vt[d * 72 + ((32 + quad * 8) ^ sg)]);
            oacc[c] = __builtin_amdgcn_mfma_f32_16x16x32_bf16(pa0, vb0, oacc[c], 0, 0, 0);
            oacc[c] = __builtin_amdgcn_mfma_f32_16x16x32_bf16(pa1, vb1, oacc[c], 0, 0, 0);
        }
    }
    #pragma unroll
    for (int c = 0; c < 4; ++c) {
        const int e = h * DH_ + c * 16 + l15;
        #pragma unroll
        for (int r = 0; r < 4; ++r) {
            const int qg = qt * 64 + wv * 16 + quad * 4 + r;
            ctx[((size_t)b * S_ + qg) * E_ + e] = f2bf(oacc[c][r] / lrun[r]);
        }
    }
}

// ---------------------------------------------------------------------------
extern "C" void kernel_launch(void* const* d_in, const int* in_sizes, int n_in,
                              void* d_out, int out_size, void* d_ws, size_t ws_size,
                              hipStream_t stream)
{
    const float* query = (const float*)d_in[0];
    const float* key   = (const float*)d_in[1];
    const float* value = (const float*)d_in[2];
    const int*   mask  = (const int*)d_in[3];
    const float* Wq = (const float*)d_in[4];  const float* bq = (const float*)d_in[5];
    const float* Wk = (const float*)d_in[6];  const float* bk = (const float*)d_in[7];
    const float* Wv = (const float*)d_in[8];  const float* bv = (const float*)d_in[9];
    const float* Wo = (const float*)d_in[10]; const float* bo = (const float*)d_in[11];
    float* out = (float*)d_out;

    u16* ws = (u16*)d_ws;
    dim3 blk(256);
    dim3 blk512(512);

    const size_t need_fancy = (size_t)(6 * MELEMS + 4 * WE) * sizeof(u16);  // 56 MB
    const size_t need_full  = (size_t)(4 * MELEMS) * sizeof(u16) + 64;      // 33.6 MB

    if (ws_size >= need_fancy) {
        u16* Qi  = ws;
        u16* Ki  = Qi + MELEMS;
        u16* Vi  = Ki + MELEMS;
        u16* Wqt = Vi + MELEMS;
        u16* Wkt = Wqt + WE;
        u16* Wvt = Wkt + WE;
        u16* Wot = Wvt + WE;
        u16* Qp  = Wot + WE;
        u16* Kp  = Qp + MELEMS;
        u16* Vp  = Kp + MELEMS;   // holds V^T [B][E][S]
        u16* Cp  = Qi;            // alias: Qi/Ki/Vi dead after QKV GEMMs

        cvt_all<<<dim3(7168), blk, 0, stream>>>(query, key, value,
                                                Wq, Wk, Wv, Wo,
                                                Qi, Ki, Vi, Wqt, Wkt, Wvt, Wot);

        gemm_bt64<64><<<dim3(16, 32, 3), blk512, 0, stream>>>(
            Qi, Ki, Vi, Wqt, Wkt, Wvt, bq, bk, bv,
            Qp, Kp, Vp, 0, /*vt_z=*/2, 0.125f, E_);

        attn_v11<<<dim3(S_ / 128, B_ * H_), dim3(256), 0, stream>>>(Qp, Kp, Vp, mask, Cp);

        gemm_bt64<64><<<dim3(16, 32, 1), blk512, 0, stream>>>(
            Cp, Cp, Cp, Wot, Wot, Wot, bo, bo, bo,
            out, out, out, 1, /*vt_z=*/-1, 1.0f, E_);
    } else if (ws_size >= need_full) {
        u16* Qp = ws;
        u16* Kp = ws + MELEMS;
        u16* Vp = ws + 2 * MELEMS;
        u16* Cp = ws + 3 * MELEMS;
        const int M = B_ * S_;
        dim3 gg(E_ / 64, M / 64);
        gemm_bias<<<gg, blk, 0, stream>>>(query, 1, Wq, bq, Qp, 0, M, E_, E_, 0.125f);
        gemm_bias<<<gg, blk, 0, stream>>>(key,   1, Wk, bk, Kp, 0, M, E_, E_, 1.0f);
        gemm_bias<<<gg, blk, 0, stream>>>(value, 1, Wv, bv, Vp, 0, M, E_, E_, 1.0f);
        attn_v2<<<dim3(S_ / 64, B_ * H_), blk, 0, stream>>>(Qp, Kp, Vp, mask, Cp, H_);
        gemm_bias<<<gg, blk, 0, stream>>>(Cp, 0, Wo, bo, out, 1, M, E_, E_, 1.0f);
    } else {
        const size_t szb = (size_t)S_ * E_;
        u16* Qp = ws; u16* Kp = ws + szb; u16* Vp = ws + 2 * szb; u16* Cp = ws + 3 * szb;
        dim3 gg(E_ / 64, S_ / 64);
        for (int b = 0; b < B_; ++b) {
            gemm_bias<<<gg, blk, 0, stream>>>(query + b * szb, 1, Wq, bq, Qp, 0, S_, E_, E_, 0.125f);
            gemm_bias<<<gg, blk, 0, stream>>>(key   + b * szb, 1, Wk, bk, Kp, 0, S_, E_, E_, 1.0f);
            gemm_bias<<<gg, blk, 0, stream>>>(value + b * szb, 1, Wv, bv, Vp, 0, S_, E_, E_, 1.0f);
            attn_v2<<<dim3(S_ / 64, H_), blk, 0, stream>>>(Qp, Kp, Vp, mask + b * S_, Cp, H_);
            gemm_bias<<<gg, blk, 0, stream>>>(Cp, 0, Wo, bo, ((float*)d_out) + b * szb, 1, S_, E_, E_, 1.0f);
        }
    }
}